// Round 2
// baseline (11275.226 us; speedup 1.0000x reference)
//
#include <hip/hip_runtime.h>
#include <hip/hip_bf16.h>

#define B_ 4
#define L_ 4096
#define C_ 2048
#define NH_ 32
#define K_ 16
#define F_ 64
#define NC_ 256
#define EPS_ 1e-6f

__device__ __forceinline__ float wave_sum64(float v) {
#pragma unroll
  for (int o = 32; o > 0; o >>= 1) v += __shfl_xor(v, o, 64);
  return v;
}

// ---------------- GEMM: C[m,n] = sum_k A[m,k]*B[n,k]  (A: MxKd, B: NxKd) ----
#define GBM 128
#define GBN 128
#define GBK 8

__global__ __launch_bounds__(256) void gemm_bt(
    const float* __restrict__ A, const float* __restrict__ Bm,
    float* __restrict__ C, int M, int N, int Kd)
{
  __shared__ float As[GBK][GBM];
  __shared__ float Bs[GBK][GBN];
  const int t  = threadIdx.x;
  const int bn = blockIdx.x, bm = blockIdx.y;
  const int tx = t & 15, ty = t >> 4;
  const int lrow = t >> 1;          // 0..127
  const int lcol = (t & 1) * 4;     // 0 or 4

  const float* Ap = A  + (size_t)(bm * GBM + lrow) * Kd + lcol;
  const float* Bp = Bm + (size_t)(bn * GBN + lrow) * Kd + lcol;

  float acc[8][8];
#pragma unroll
  for (int i = 0; i < 8; ++i)
#pragma unroll
    for (int j = 0; j < 8; ++j) acc[i][j] = 0.f;

  for (int k0 = 0; k0 < Kd; k0 += GBK) {
    float4 av = *(const float4*)(Ap + k0);
    float4 bv = *(const float4*)(Bp + k0);
    __syncthreads();
    As[lcol+0][lrow]=av.x; As[lcol+1][lrow]=av.y; As[lcol+2][lrow]=av.z; As[lcol+3][lrow]=av.w;
    Bs[lcol+0][lrow]=bv.x; Bs[lcol+1][lrow]=bv.y; Bs[lcol+2][lrow]=bv.z; Bs[lcol+3][lrow]=bv.w;
    __syncthreads();
#pragma unroll
    for (int kk = 0; kk < GBK; ++kk) {
      float4 a0 = *(const float4*)&As[kk][ty*8];
      float4 a1 = *(const float4*)&As[kk][ty*8+4];
      float4 b0 = *(const float4*)&Bs[kk][tx*8];
      float4 b1 = *(const float4*)&Bs[kk][tx*8+4];
      float am[8]  = {a0.x,a0.y,a0.z,a0.w,a1.x,a1.y,a1.z,a1.w};
      float bnv[8] = {b0.x,b0.y,b0.z,b0.w,b1.x,b1.y,b1.z,b1.w};
#pragma unroll
      for (int i = 0; i < 8; ++i)
#pragma unroll
        for (int j = 0; j < 8; ++j) acc[i][j] += am[i]*bnv[j];
    }
  }
#pragma unroll
  for (int i = 0; i < 8; ++i) {
    float* cp = C + (size_t)(bm*GBM + ty*8 + i) * N + bn*GBN + tx*8;
    *(float4*)(cp)   = make_float4(acc[i][0],acc[i][1],acc[i][2],acc[i][3]);
    *(float4*)(cp+4) = make_float4(acc[i][4],acc[i][5],acc[i][6],acc[i][7]);
  }
}

// ---------------- ilr / coeff ----------------
__global__ __launch_bounds__(256) void ilr_kernel(
    const float* __restrict__ hid, const float* __restrict__ lin_w,
    const float* __restrict__ lin_b, float* __restrict__ coeff)
{
  const int t = threadIdx.x;
  const int lane = t & 63;
  const int w = t >> 6;
  const int row0 = blockIdx.x * 16 + w * 4;   // 4 rows per wave

  float4 hv[4][8];
#pragma unroll
  for (int r = 0; r < 4; ++r) {
    const float* hp = hid + (size_t)(row0 + r) * C_;
#pragma unroll
    for (int i = 0; i < 8; ++i) hv[r][i] = *(const float4*)(hp + i*256 + lane*4);
  }
  float res[4] = {0.f,0.f,0.f,0.f};
  for (int h = 0; h < NH_; ++h) {
    const float* wp = lin_w + (size_t)h * C_;
    float s[4] = {0.f,0.f,0.f,0.f};
#pragma unroll
    for (int i = 0; i < 8; ++i) {
      float4 wv = *(const float4*)(wp + i*256 + lane*4);
#pragma unroll
      for (int r = 0; r < 4; ++r)
        s[r] += hv[r][i].x*wv.x + hv[r][i].y*wv.y + hv[r][i].z*wv.z + hv[r][i].w*wv.w;
    }
#pragma unroll
    for (int o = 32; o > 0; o >>= 1)
#pragma unroll
      for (int r = 0; r < 4; ++r) s[r] += __shfl_xor(s[r], o, 64);
    if (lane == h) { res[0]=s[0]; res[1]=s[1]; res[2]=s[2]; res[3]=s[3]; }
  }
  if (lane < NH_) {
    float lb = lin_b[lane];
#pragma unroll
    for (int r = 0; r < 4; ++r) {
      int row = row0 + r;
      int b = row >> 12;            // L_ = 4096
      int li = row & (L_ - 1);
      int k = li & (K_ - 1);
      float x = res[r] + lb;
      float sp = (x > 20.f) ? x : log1pf(expf(x));
      float v = (1.0f / (float)(k + 1)) * sp * (1.0f / (float)F_);
      coeff[((size_t)(b * NH_ + lane)) * L_ + li] = v;
    }
  }
}

// ---------------- sequential TTT scan: one block per (b,h) ----------------
// VIO: V on input; overwritten in-place with the per-head output (same flat
// index: element (b, l, h*F+f) read in phase A of chunk n, written in phase G
// of the same chunk; blocks own disjoint (b, h) slices).
__global__ __launch_bounds__(256) void scan_kernel(
    const float* __restrict__ Q, const float* __restrict__ Kp, float* VIO,
    const float* __restrict__ coeff, const float* __restrict__ W1g, const float* __restrict__ b1g,
    const float* __restrict__ ln_w, const float* __restrict__ ln_b)
{
  const int bh = blockIdx.x;
  const int b = bh / NH_, h = bh % NH_;
  const int t = threadIdx.x;
  const int lane = t & 63;
  const int w = t >> 6;

  __shared__ float W1s[F_][F_];
  __shared__ float xa[K_][F_], xb[K_][F_+4], xc[K_][F_+4], gZ[K_][F_];
  __shared__ float attn[K_][K_+1];
  __shared__ float cov[K_];
  __shared__ float b1s[F_], gam[F_], bet[F_], b1b15[F_];

  for (int i = t; i < F_*F_; i += 256) W1s[i>>6][i&63] = W1g[(size_t)h*F_*F_ + i];
  if (t < F_) { b1s[t] = b1g[h*F_+t]; gam[t] = ln_w[h*F_+t]; bet[t] = ln_b[h*F_+t]; }
  __syncthreads();

  const size_t baserow = (size_t)b * L_;
  for (int n = 0; n < NC_; ++n) {
    // ---- A: load chunk
    {
      int row = t >> 4; int f4 = (t & 15) * 4;
      size_t gidx = (baserow + (size_t)n*K_ + row) * C_ + h*F_ + f4;
      float4 va = *(const float4*)(VIO + gidx);
      float4 vb = *(const float4*)(Kp + gidx);
      float4 vc = *(const float4*)(Q  + gidx);
      *(float4*)&xa[row][f4] = va;
      *(float4*)&xb[row][f4] = vb;
      *(float4*)&xc[row][f4] = vc;
      if (t < K_) cov[t] = coeff[(size_t)bh * L_ + (size_t)n*K_ + t];
    }
    __syncthreads();

    // ---- B: Z1 = xb@W1 + b1  (rows k=w*4+r, col=lane), kept in regs
    float z[4];
#pragma unroll
    for (int r = 0; r < 4; ++r) {
      const int k = w*4 + r;
      float acc = b1s[lane];
#pragma unroll
      for (int g = 0; g < F_; g += 4) {
        float4 vb = *(const float4*)&xb[k][g];
        acc += vb.x*W1s[g+0][lane] + vb.y*W1s[g+1][lane]
             + vb.z*W1s[g+2][lane] + vb.w*W1s[g+3][lane];
      }
      z[r] = acc;
    }

    // ---- D: Attn1[k][j] = xc[k]·xb[j] (j<=k)
    {
      const int k = t >> 4, j = t & 15;
      float a = 0.f;
      if (j <= k) {
#pragma unroll
        for (int f = 0; f < F_; ++f) a += xc[k][f]*xb[j][f];
      }
      attn[k][j] = a;
    }

    // ---- C: LN-L2 backward per row -> gZ
#pragma unroll
    for (int r = 0; r < 4; ++r) {
      const int k = w*4 + r;
      float zz = z[r];
      float mu = wave_sum64(zz) * (1.f/F_);
      float d  = zz - mu;
      float var = wave_sum64(d*d) * (1.f/F_);
      float istd = rsqrtf(var + EPS_);
      float xh = d * istd;
      float g_ = gam[lane];
      float gy = (g_*xh + bet[lane] - (xa[k][lane] - xb[k][lane])) * g_;
      float sgy   = wave_sum64(gy);
      float sgyxh = wave_sum64(gy*xh);
      gZ[k][lane] = (F_*gy - sgy - xh*sgyxh) * (istd * (1.f/F_));
    }
    __syncthreads();

    // ---- E: Z1_bar (rows k=w*4+r), b1_bar; uses OLD W1,b1
    float zb[4];
#pragma unroll
    for (int r = 0; r < 4; ++r) {
      const int k = w*4 + r;
      float acc = 0.f;
#pragma unroll
      for (int g = 0; g < F_; g += 4) {
        float4 vc = *(const float4*)&xc[k][g];
        acc += vc.x*W1s[g+0][lane] + vc.y*W1s[g+1][lane]
             + vc.z*W1s[g+2][lane] + vc.w*W1s[g+3][lane];
      }
      float cum = 0.f, ag = 0.f;
      for (int j = 0; j <= k; ++j) {
        float gv = gZ[j][lane];
        cum += gv;
        ag  += attn[k][j]*gv;
      }
      float bb = b1s[lane] - cov[k]*cum;
      zb[r] = acc - cov[k]*ag + bb;
      if (k == K_-1) b1b15[lane] = bb;
    }
    __syncthreads();

    // ---- F: state update W1 -= co15 * xb^T @ gZ ; b1 = b1_bar[15]
    {
      const float c15 = cov[K_-1];
      float gzv[K_];
#pragma unroll
      for (int k = 0; k < K_; ++k) gzv[k] = gZ[k][lane];
#pragma unroll
      for (int gi = 0; gi < 16; ++gi) {
        const int g = w*16 + gi;
        float s = 0.f;
#pragma unroll
        for (int k = 0; k < K_; ++k) s += xb[k][g]*gzv[k];
        W1s[g][lane] -= c15 * s;
      }
      if (w == 0) b1s[lane] = b1b15[lane];
    }

    // ---- G: out = xc + LN(Z1_bar), written in-place over V
#pragma unroll
    for (int r = 0; r < 4; ++r) {
      const int k = w*4 + r;
      float zz = zb[r];
      float mu = wave_sum64(zz) * (1.f/F_);
      float d  = zz - mu;
      float var = wave_sum64(d*d) * (1.f/F_);
      float istd = rsqrtf(var + EPS_);
      float xh = d * istd;
      float o = xc[k][lane] + gam[lane]*xh + bet[lane];
      VIO[(baserow + (size_t)n*K_ + k)*C_ + h*F_ + lane] = o;
    }
    __syncthreads();
  }
}

extern "C" void kernel_launch(void* const* d_in, const int* in_sizes, int n_in,
                              void* d_out, int out_size, void* d_ws, size_t ws_size,
                              hipStream_t stream)
{
  const float* hid   = (const float*)d_in[0];
  const float* q_w   = (const float*)d_in[1];
  const float* k_w   = (const float*)d_in[2];
  const float* v_w   = (const float*)d_in[3];
  const float* o_w   = (const float*)d_in[4];
  const float* lin_w = (const float*)d_in[5];
  const float* lin_b = (const float*)d_in[6];
  const float* ln_w  = (const float*)d_in[7];
  const float* ln_b  = (const float*)d_in[8];
  const float* W1    = (const float*)d_in[9];
  const float* b1    = (const float*)d_in[10];
  float* out = (float*)d_out;

  const size_t BLC = (size_t)B_ * L_ * C_;
  float* wsf = (float*)d_ws;
  float* Q  = out;               // d_out doubles as Q scratch (dead before final GEMM)
  float* Kp = wsf;
  float* V  = Kp + BLC;          // V doubles as the per-head output buffer
  float* CO = V  + BLC;          // B*NH*L floats

  const int M = B_ * L_, N = C_, Kd = C_;
  dim3 gg(N / GBN, M / GBM);

  gemm_bt<<<gg, 256, 0, stream>>>(hid, q_w, Q,  M, N, Kd);
  gemm_bt<<<gg, 256, 0, stream>>>(hid, k_w, Kp, M, N, Kd);
  gemm_bt<<<gg, 256, 0, stream>>>(hid, v_w, V,  M, N, Kd);
  ilr_kernel<<<M / 16, 256, 0, stream>>>(hid, lin_w, lin_b, CO);
  scan_kernel<<<B_ * NH_, 256, 0, stream>>>(Q, Kp, V, CO, W1, b1, ln_w, ln_b);
  gemm_bt<<<gg, 256, 0, stream>>>(V, o_w, out, M, N, Kd);
}

// Round 3
// 8902.266 us; speedup vs baseline: 1.2666x; 1.2666x over previous
//
#include <hip/hip_runtime.h>
#include <hip/hip_bf16.h>

#define B_ 4
#define L_ 4096
#define C_ 2048
#define NH_ 32
#define K_ 16
#define F_ 64
#define NC_ 256
#define EPS_ 1e-6f

__device__ __forceinline__ float wave_sum64(float v) {
#pragma unroll
  for (int o = 32; o > 0; o >>= 1) v += __shfl_xor(v, o, 64);
  return v;
}

// ---------------- GEMM: C[m,n] = sum_k A[m,k]*B[n,k]  (A: MxKd, B: NxKd) ----
#define GBM 128
#define GBN 128
#define GBK 8

__global__ __launch_bounds__(256) void gemm_bt(
    const float* __restrict__ A, const float* __restrict__ Bm,
    float* __restrict__ C, int M, int N, int Kd)
{
  __shared__ float As[GBK][GBM];
  __shared__ float Bs[GBK][GBN];
  const int t  = threadIdx.x;
  const int bn = blockIdx.x, bm = blockIdx.y;
  const int tx = t & 15, ty = t >> 4;
  const int lrow = t >> 1;          // 0..127
  const int lcol = (t & 1) * 4;     // 0 or 4

  const float* Ap = A  + (size_t)(bm * GBM + lrow) * Kd + lcol;
  const float* Bp = Bm + (size_t)(bn * GBN + lrow) * Kd + lcol;

  float acc[8][8];
#pragma unroll
  for (int i = 0; i < 8; ++i)
#pragma unroll
    for (int j = 0; j < 8; ++j) acc[i][j] = 0.f;

  for (int k0 = 0; k0 < Kd; k0 += GBK) {
    float4 av = *(const float4*)(Ap + k0);
    float4 bv = *(const float4*)(Bp + k0);
    __syncthreads();
    As[lcol+0][lrow]=av.x; As[lcol+1][lrow]=av.y; As[lcol+2][lrow]=av.z; As[lcol+3][lrow]=av.w;
    Bs[lcol+0][lrow]=bv.x; Bs[lcol+1][lrow]=bv.y; Bs[lcol+2][lrow]=bv.z; Bs[lcol+3][lrow]=bv.w;
    __syncthreads();
#pragma unroll
    for (int kk = 0; kk < GBK; ++kk) {
      float4 a0 = *(const float4*)&As[kk][ty*8];
      float4 a1 = *(const float4*)&As[kk][ty*8+4];
      float4 b0 = *(const float4*)&Bs[kk][tx*8];
      float4 b1 = *(const float4*)&Bs[kk][tx*8+4];
      float am[8]  = {a0.x,a0.y,a0.z,a0.w,a1.x,a1.y,a1.z,a1.w};
      float bnv[8] = {b0.x,b0.y,b0.z,b0.w,b1.x,b1.y,b1.z,b1.w};
#pragma unroll
      for (int i = 0; i < 8; ++i)
#pragma unroll
        for (int j = 0; j < 8; ++j) acc[i][j] += am[i]*bnv[j];
    }
  }
#pragma unroll
  for (int i = 0; i < 8; ++i) {
    float* cp = C + (size_t)(bm*GBM + ty*8 + i) * N + bn*GBN + tx*8;
    *(float4*)(cp)   = make_float4(acc[i][0],acc[i][1],acc[i][2],acc[i][3]);
    *(float4*)(cp+4) = make_float4(acc[i][4],acc[i][5],acc[i][6],acc[i][7]);
  }
}

// ---------------- ilr / coeff ----------------
__global__ __launch_bounds__(256) void ilr_kernel(
    const float* __restrict__ hid, const float* __restrict__ lin_w,
    const float* __restrict__ lin_b, float* __restrict__ coeff)
{
  const int t = threadIdx.x;
  const int lane = t & 63;
  const int w = t >> 6;
  const int row0 = blockIdx.x * 16 + w * 4;   // 4 rows per wave

  float4 hv[4][8];
#pragma unroll
  for (int r = 0; r < 4; ++r) {
    const float* hp = hid + (size_t)(row0 + r) * C_;
#pragma unroll
    for (int i = 0; i < 8; ++i) hv[r][i] = *(const float4*)(hp + i*256 + lane*4);
  }
  float res[4] = {0.f,0.f,0.f,0.f};
  for (int h = 0; h < NH_; ++h) {
    const float* wp = lin_w + (size_t)h * C_;
    float s[4] = {0.f,0.f,0.f,0.f};
#pragma unroll
    for (int i = 0; i < 8; ++i) {
      float4 wv = *(const float4*)(wp + i*256 + lane*4);
#pragma unroll
      for (int r = 0; r < 4; ++r)
        s[r] += hv[r][i].x*wv.x + hv[r][i].y*wv.y + hv[r][i].z*wv.z + hv[r][i].w*wv.w;
    }
#pragma unroll
    for (int o = 32; o > 0; o >>= 1)
#pragma unroll
      for (int r = 0; r < 4; ++r) s[r] += __shfl_xor(s[r], o, 64);
    if (lane == h) { res[0]=s[0]; res[1]=s[1]; res[2]=s[2]; res[3]=s[3]; }
  }
  if (lane < NH_) {
    float lb = lin_b[lane];
#pragma unroll
    for (int r = 0; r < 4; ++r) {
      int row = row0 + r;
      int b = row >> 12;            // L_ = 4096
      int li = row & (L_ - 1);
      int k = li & (K_ - 1);
      float x = res[r] + lb;
      float sp = (x > 20.f) ? x : log1pf(expf(x));
      float v = (1.0f / (float)(k + 1)) * sp * (1.0f / (float)F_);
      coeff[((size_t)(b * NH_ + lane)) * L_ + li] = v;
    }
  }
}

// ---------------- TTT scan v2: W1 column replicated in registers ----------
// VIO: V on input; overwritten in-place with per-head output (same flat index,
// read phase A before write phase G, blocks own disjoint (b,h) slices).
__global__ __launch_bounds__(256) void scan_kernel(
    const float* __restrict__ Q, const float* __restrict__ Kp, float* VIO,
    const float* __restrict__ coeff, const float* __restrict__ W1g, const float* __restrict__ b1g,
    const float* __restrict__ ln_w, const float* __restrict__ ln_b)
{
  const int bh = blockIdx.x;
  const int b = bh / NH_, h = bh % NH_;
  const int t = threadIdx.x;
  const int lane = t & 63;
  const int w = t >> 6;

  __shared__ float xa[K_][F_+4], xb[K_][F_+4], xc[K_][F_+4];
  __shared__ float gZ[K_][F_];
  __shared__ float attn[K_][K_+1];
  __shared__ float delta[F_][F_];
  __shared__ float b1b15[F_];

  // register state: this thread owns column `lane` of W1 (all 64 rows)
  float W1c[F_];
#pragma unroll
  for (int g = 0; g < F_; ++g) W1c[g] = W1g[(size_t)h*F_*F_ + g*F_ + lane];
  float b1r  = b1g[h*F_ + lane];
  const float gamr = ln_w[h*F_ + lane];
  const float betr = ln_b[h*F_ + lane];

  // load-phase assignment
  const int lrow = t >> 4;            // 0..15
  const int lf4  = (t & 15) * 4;      // 0..60 step 4
  const size_t gbase = ((size_t)b*L_ + lrow)*C_ + h*F_ + lf4;
  const size_t obase = ((size_t)b*L_)*C_ + h*F_ + lane;
  const size_t cbase = (size_t)bh * L_;

  // prefetch chunk 0
  float4 pa = *(const float4*)(VIO + gbase);
  float4 pb = *(const float4*)(Kp  + gbase);
  float4 pc = *(const float4*)(Q   + gbase);
  float covr[4], cov15;
#pragma unroll
  for (int r = 0; r < 4; ++r) covr[r] = coeff[cbase + w*4 + r];
  cov15 = coeff[cbase + 15];

  for (int n = 0; n < NC_; ++n) {
    // ---- A: commit prefetched tile to LDS
    *(float4*)&xa[lrow][lf4] = pa;
    *(float4*)&xb[lrow][lf4] = pb;
    *(float4*)&xc[lrow][lf4] = pc;
    __syncthreads();                       // #1

    // issue prefetch for chunk n+1 (regs only, no LDS)
    {
      const int np = (n + 1 < NC_) ? n + 1 : n;
      const size_t off = (size_t)np * K_ * C_;
      pa = *(const float4*)(VIO + gbase + off);
      pb = *(const float4*)(Kp  + gbase + off);
      pc = *(const float4*)(Q   + gbase + off);
    }
    float covn[4], cov15n;
    {
      const int np = (n + 1 < NC_) ? n + 1 : n;
#pragma unroll
      for (int r = 0; r < 4; ++r) covn[r] = coeff[cbase + (size_t)np*K_ + w*4 + r];
      cov15n = coeff[cbase + (size_t)np*K_ + 15];
    }

    // ---- B: z[r] = xb[k] @ W1col + b1   (k = w*4+r, out col = lane)
    float z[4];
#pragma unroll
    for (int r = 0; r < 4; ++r) {
      const int k = w*4 + r;
      float acc = b1r;
#pragma unroll
      for (int g4 = 0; g4 < 16; ++g4) {
        float4 xv = *(const float4*)&xb[k][4*g4];
        acc += xv.x*W1c[4*g4+0] + xv.y*W1c[4*g4+1]
             + xv.z*W1c[4*g4+2] + xv.w*W1c[4*g4+3];
      }
      z[r] = acc;
    }

    // ---- D: attn[k][j] = xc[k] . xb[j]
    {
      const int dk = t >> 4, dj = t & 15;
      float a = 0.f;
#pragma unroll
      for (int f4 = 0; f4 < 16; ++f4) {
        float4 cv = *(const float4*)&xc[dk][4*f4];
        float4 bv = *(const float4*)&xb[dj][4*f4];
        a += cv.x*bv.x + cv.y*bv.y + cv.z*bv.z + cv.w*bv.w;
      }
      attn[dk][dj] = a;
    }

    // ---- C: LN-L2 backward -> gZ
#pragma unroll
    for (int r = 0; r < 4; ++r) {
      const int k = w*4 + r;
      float zz = z[r];
      float mu = wave_sum64(zz) * (1.f/F_);
      float d  = zz - mu;
      float var = wave_sum64(d*d) * (1.f/F_);
      float istd = rsqrtf(var + EPS_);
      float xh = d * istd;
      float gy = (gamr*xh + betr - (xa[k][lane] - xb[k][lane])) * gamr;
      float sgy   = wave_sum64(gy);
      float sgyxh = wave_sum64(gy*xh);
      gZ[k][lane] = (F_*gy - sgy - xh*sgyxh) * (istd * (1.f/F_));
    }
    __syncthreads();                       // #2

    // gZ column into regs (reused by E and F)
    float gzr[K_];
#pragma unroll
    for (int j = 0; j < K_; ++j) gzr[j] = gZ[j][lane];

    // ---- E: Z1_bar rows k=w*4+r
    float zb[4];
#pragma unroll
    for (int r = 0; r < 4; ++r) {
      const int k = w*4 + r;
      float acc = 0.f;
#pragma unroll
      for (int g4 = 0; g4 < 16; ++g4) {
        float4 cv = *(const float4*)&xc[k][4*g4];
        acc += cv.x*W1c[4*g4+0] + cv.y*W1c[4*g4+1]
             + cv.z*W1c[4*g4+2] + cv.w*W1c[4*g4+3];
      }
      float cum = 0.f, ag = 0.f;
#pragma unroll
      for (int j = 0; j < K_; ++j) {
        if (j <= k) { cum += gzr[j]; ag += attn[k][j]*gzr[j]; }
      }
      float bb = b1r - covr[r]*cum;
      zb[r] = acc - covr[r]*ag + bb;
      if (k == K_-1) b1b15[lane] = bb;
    }

    // ---- G: out = xc + LN(Z1_bar), in-place over V
#pragma unroll
    for (int r = 0; r < 4; ++r) {
      const int k = w*4 + r;
      float zz = zb[r];
      float mu = wave_sum64(zz) * (1.f/F_);
      float d  = zz - mu;
      float var = wave_sum64(d*d) * (1.f/F_);
      float istd = rsqrtf(var + EPS_);
      float xh = d * istd;
      VIO[obase + (size_t)(n*K_ + k)*C_] = xc[k][lane] + gamr*xh + betr;
    }

    // ---- F: delta[g][lane] = sum_k xb[k][g]*gZ[k][lane]; wave w does rows w*16..+15
    {
      float dl[16];
#pragma unroll
      for (int i = 0; i < 16; ++i) dl[i] = 0.f;
#pragma unroll
      for (int k = 0; k < K_; ++k) {
        const float gk = gzr[k];
#pragma unroll
        for (int q = 0; q < 4; ++q) {
          float4 bv = *(const float4*)&xb[k][w*16 + 4*q];
          dl[4*q+0] += bv.x*gk; dl[4*q+1] += bv.y*gk;
          dl[4*q+2] += bv.z*gk; dl[4*q+3] += bv.w*gk;
        }
      }
#pragma unroll
      for (int i = 0; i < 16; ++i) delta[w*16 + i][lane] = dl[i];
    }
    __syncthreads();                       // #3

    // apply update; reload b1
    {
      const float c15 = cov15;
#pragma unroll
      for (int g = 0; g < F_; ++g) W1c[g] -= c15 * delta[g][lane];
      b1r = b1b15[lane];
    }
#pragma unroll
    for (int r = 0; r < 4; ++r) covr[r] = covn[r];
    cov15 = cov15n;
  }
}

extern "C" void kernel_launch(void* const* d_in, const int* in_sizes, int n_in,
                              void* d_out, int out_size, void* d_ws, size_t ws_size,
                              hipStream_t stream)
{
  const float* hid   = (const float*)d_in[0];
  const float* q_w   = (const float*)d_in[1];
  const float* k_w   = (const float*)d_in[2];
  const float* v_w   = (const float*)d_in[3];
  const float* o_w   = (const float*)d_in[4];
  const float* lin_w = (const float*)d_in[5];
  const float* lin_b = (const float*)d_in[6];
  const float* ln_w  = (const float*)d_in[7];
  const float* ln_b  = (const float*)d_in[8];
  const float* W1    = (const float*)d_in[9];
  const float* b1    = (const float*)d_in[10];
  float* out = (float*)d_out;

  const size_t BLC = (size_t)B_ * L_ * C_;
  float* wsf = (float*)d_ws;
  float* Q  = out;               // d_out doubles as Q scratch (dead before final GEMM)
  float* Kp = wsf;
  float* V  = Kp + BLC;          // V doubles as the per-head output buffer
  float* CO = V  + BLC;          // B*NH*L floats

  const int M = B_ * L_, N = C_, Kd = C_;
  dim3 gg(N / GBN, M / GBM);

  gemm_bt<<<gg, 256, 0, stream>>>(hid, q_w, Q,  M, N, Kd);
  gemm_bt<<<gg, 256, 0, stream>>>(hid, k_w, Kp, M, N, Kd);
  gemm_bt<<<gg, 256, 0, stream>>>(hid, v_w, V,  M, N, Kd);
  ilr_kernel<<<M / 16, 256, 0, stream>>>(hid, lin_w, lin_b, CO);
  scan_kernel<<<B_ * NH_, 256, 0, stream>>>(Q, Kp, V, CO, W1, b1, ln_w, ln_b);
  gemm_bt<<<gg, 256, 0, stream>>>(V, o_w, out, M, N, Kd);
}

// Round 4
// 3201.937 us; speedup vs baseline: 3.5214x; 2.7803x over previous
//
#include <hip/hip_runtime.h>
#include <hip/hip_bf16.h>

#define B_ 4
#define L_ 4096
#define C_ 2048
#define NH_ 32
#define K_ 16
#define F_ 64
#define NC_ 256
#define EPS_ 1e-6f

typedef _Float16 half8 __attribute__((ext_vector_type(8)));
typedef _Float16 half4 __attribute__((ext_vector_type(4)));
typedef float f32x4 __attribute__((ext_vector_type(4)));

__device__ __forceinline__ float wave_sum64(float v) {
#pragma unroll
  for (int o = 32; o > 0; o >>= 1) v += __shfl_xor(v, o, 64);
  return v;
}

__device__ __forceinline__ void gl_lds16(const _Float16* g, _Float16* l) {
  __builtin_amdgcn_global_load_lds(
      (const __attribute__((address_space(1))) void*)g,
      (__attribute__((address_space(3))) void*)l, 16, 0, 0);
}

// ---------------- cast fp32 -> f16, 8 elems/thread ----------------
__global__ __launch_bounds__(256) void cast_f16(const float* __restrict__ in,
                                                _Float16* __restrict__ out, int n8) {
  int i = blockIdx.x * 256 + threadIdx.x;
  if (i >= n8) return;
  const float4* ip = (const float4*)in;
  float4 a = ip[2*i], b = ip[2*i+1];
  half8 o;
  o[0]=(_Float16)a.x; o[1]=(_Float16)a.y; o[2]=(_Float16)a.z; o[3]=(_Float16)a.w;
  o[4]=(_Float16)b.x; o[5]=(_Float16)b.y; o[6]=(_Float16)b.z; o[7]=(_Float16)b.w;
  ((half8*)out)[i] = o;
}

// ---------------- f16 MFMA GEMM: C[m,n] = sum_k A[m,k]*B[n,k] ----------------
// m97 structure: 128x128 tile, BK=32, 4 waves (2x2 of 64x64), global_load_lds(16B).
#define TM 128
#define TN 128
#define TK 32

template<typename OT>
__global__ __launch_bounds__(256) void gemm_f16(
    const _Float16* __restrict__ A, const _Float16* __restrict__ Bm,
    OT* __restrict__ C, int M, int N, int Kd)
{
  __shared__ __align__(16) _Float16 As[TM*TK];   // 8 KB, row-major [128][32]
  __shared__ __align__(16) _Float16 Bs[TN*TK];   // 8 KB
  const int t = threadIdx.x;
  const int lane = t & 63;
  const int bn = blockIdx.x, bm = blockIdx.y;
  const int w = t >> 6;
  const int wm = (w >> 1) * 64, wn = (w & 1) * 64;

  // staging: chunk c -> LDS bytes [c*16, c*16+16), global row c>>2, k-offset (c&3)*8
  const _Float16* ga1 = A  + ((long)(bm*TM +      (t>>2)))*Kd + (t&3)*8;
  const _Float16* ga2 = A  + ((long)(bm*TM + 64 + (t>>2)))*Kd + (t&3)*8;
  const _Float16* gb1 = Bm + ((long)(bn*TN +      (t>>2)))*Kd + (t&3)*8;
  const _Float16* gb2 = Bm + ((long)(bn*TN + 64 + (t>>2)))*Kd + (t&3)*8;
  _Float16* la1 = As + (size_t)t*8;
  _Float16* la2 = As + (size_t)(t+256)*8;
  _Float16* lb1 = Bs + (size_t)t*8;
  _Float16* lb2 = Bs + (size_t)(t+256)*8;

  f32x4 acc[4][4];
#pragma unroll
  for (int i = 0; i < 4; ++i)
#pragma unroll
    for (int j = 0; j < 4; ++j) acc[i][j] = (f32x4){0.f,0.f,0.f,0.f};

  for (int k0 = 0; k0 < Kd; k0 += TK) {
    __syncthreads();                 // previous iter's frag reads done
    gl_lds16(ga1 + k0, la1);
    gl_lds16(ga2 + k0, la2);
    gl_lds16(gb1 + k0, lb1);
    gl_lds16(gb2 + k0, lb2);
    __syncthreads();                 // compiler drains vmcnt before barrier
    half8 af[4], bf[4];
#pragma unroll
    for (int i = 0; i < 4; ++i)
      af[i] = *(const half8*)(As + (size_t)(wm + i*16 + (lane&15))*TK + (lane>>4)*8);
#pragma unroll
    for (int j = 0; j < 4; ++j)
      bf[j] = *(const half8*)(Bs + (size_t)(wn + j*16 + (lane&15))*TK + (lane>>4)*8);
#pragma unroll
    for (int i = 0; i < 4; ++i)
#pragma unroll
      for (int j = 0; j < 4; ++j)
        acc[i][j] = __builtin_amdgcn_mfma_f32_16x16x32_f16(af[i], bf[j], acc[i][j], 0, 0, 0);
  }

  // epilogue: C/D layout col=lane&15, row=(lane>>4)*4+reg
  const int cr = (lane >> 4) * 4, cc = lane & 15;
#pragma unroll
  for (int i = 0; i < 4; ++i)
#pragma unroll
    for (int j = 0; j < 4; ++j)
#pragma unroll
      for (int r = 0; r < 4; ++r) {
        long row = (long)bm*TM + wm + i*16 + cr + r;
        long col = (long)bn*TN + wn + j*16 + cc;
        C[row*(long)N + col] = (OT)acc[i][j][r];
      }
}

// ---------------- ilr / coeff (fp32, unchanged) ----------------
__global__ __launch_bounds__(256) void ilr_kernel(
    const float* __restrict__ hid, const float* __restrict__ lin_w,
    const float* __restrict__ lin_b, float* __restrict__ coeff)
{
  const int t = threadIdx.x;
  const int lane = t & 63;
  const int w = t >> 6;
  const int row0 = blockIdx.x * 16 + w * 4;

  float4 hv[4][8];
#pragma unroll
  for (int r = 0; r < 4; ++r) {
    const float* hp = hid + (size_t)(row0 + r) * C_;
#pragma unroll
    for (int i = 0; i < 8; ++i) hv[r][i] = *(const float4*)(hp + i*256 + lane*4);
  }
  float res[4] = {0.f,0.f,0.f,0.f};
  for (int h = 0; h < NH_; ++h) {
    const float* wp = lin_w + (size_t)h * C_;
    float s[4] = {0.f,0.f,0.f,0.f};
#pragma unroll
    for (int i = 0; i < 8; ++i) {
      float4 wv = *(const float4*)(wp + i*256 + lane*4);
#pragma unroll
      for (int r = 0; r < 4; ++r)
        s[r] += hv[r][i].x*wv.x + hv[r][i].y*wv.y + hv[r][i].z*wv.z + hv[r][i].w*wv.w;
    }
#pragma unroll
    for (int o = 32; o > 0; o >>= 1)
#pragma unroll
      for (int r = 0; r < 4; ++r) s[r] += __shfl_xor(s[r], o, 64);
    if (lane == h) { res[0]=s[0]; res[1]=s[1]; res[2]=s[2]; res[3]=s[3]; }
  }
  if (lane < NH_) {
    float lb = lin_b[lane];
#pragma unroll
    for (int r = 0; r < 4; ++r) {
      int row = row0 + r;
      int b = row >> 12;
      int li = row & (L_ - 1);
      int k = li & (K_ - 1);
      float x = res[r] + lb;
      float sp = (x > 20.f) ? x : log1pf(expf(x));
      float v = (1.0f / (float)(k + 1)) * sp * (1.0f / (float)F_);
      coeff[((size_t)(b * NH_ + lane)) * L_ + li] = v;
    }
  }
}

// ---------------- TTT scan: W1 column in registers; f16 I/O ----------------
__global__ __launch_bounds__(256) void scan_kernel(
    const _Float16* __restrict__ Q, const _Float16* __restrict__ Kp,
    const _Float16* __restrict__ V,
    const float* __restrict__ coeff, const float* __restrict__ W1g, const float* __restrict__ b1g,
    const float* __restrict__ ln_w, const float* __restrict__ ln_b,
    _Float16* __restrict__ OF)
{
  const int bh = blockIdx.x;
  const int b = bh / NH_, h = bh % NH_;
  const int t = threadIdx.x;
  const int lane = t & 63;
  const int w = t >> 6;

  __shared__ float xa[K_][F_+4], xb[K_][F_+4], xc[K_][F_+4];
  __shared__ float gZ[K_][F_];
  __shared__ float attn[K_][K_+1];
  __shared__ float delta[F_][F_];
  __shared__ float b1b15[F_];

  float W1c[F_];
#pragma unroll
  for (int g = 0; g < F_; ++g) W1c[g] = W1g[(size_t)h*F_*F_ + g*F_ + lane];
  float b1r  = b1g[h*F_ + lane];
  const float gamr = ln_w[h*F_ + lane];
  const float betr = ln_b[h*F_ + lane];

  const int lrow = t >> 4;            // 0..15
  const int lf4  = (t & 15) * 4;      // 0..60 step 4
  const size_t gbase = ((size_t)b*L_ + lrow)*C_ + h*F_ + lf4;
  const size_t obase = ((size_t)b*L_)*C_ + h*F_ + lane;
  const size_t cbase = (size_t)bh * L_;

  half4 pa = *(const half4*)(V  + gbase);
  half4 pb = *(const half4*)(Kp + gbase);
  half4 pc = *(const half4*)(Q  + gbase);
  float covr[4], cov15;
#pragma unroll
  for (int r = 0; r < 4; ++r) covr[r] = coeff[cbase + w*4 + r];
  cov15 = coeff[cbase + 15];

  for (int n = 0; n < NC_; ++n) {
    // ---- A: commit prefetched tile to LDS (f16 -> f32)
    {
      float4 fa = {(float)pa[0], (float)pa[1], (float)pa[2], (float)pa[3]};
      float4 fb = {(float)pb[0], (float)pb[1], (float)pb[2], (float)pb[3]};
      float4 fc = {(float)pc[0], (float)pc[1], (float)pc[2], (float)pc[3]};
      *(float4*)&xa[lrow][lf4] = fa;
      *(float4*)&xb[lrow][lf4] = fb;
      *(float4*)&xc[lrow][lf4] = fc;
    }
    __syncthreads();                       // #1

    {
      const int np = (n + 1 < NC_) ? n + 1 : n;
      const size_t off = (size_t)np * K_ * C_;
      pa = *(const half4*)(V  + gbase + off);
      pb = *(const half4*)(Kp + gbase + off);
      pc = *(const half4*)(Q  + gbase + off);
    }
    float covn[4], cov15n;
    {
      const int np = (n + 1 < NC_) ? n + 1 : n;
#pragma unroll
      for (int r = 0; r < 4; ++r) covn[r] = coeff[cbase + (size_t)np*K_ + w*4 + r];
      cov15n = coeff[cbase + (size_t)np*K_ + 15];
    }

    // ---- B: z[r] = xb[k] @ W1col + b1
    float z[4];
#pragma unroll
    for (int r = 0; r < 4; ++r) {
      const int k = w*4 + r;
      float acc = b1r;
#pragma unroll
      for (int g4 = 0; g4 < 16; ++g4) {
        float4 xv = *(const float4*)&xb[k][4*g4];
        acc += xv.x*W1c[4*g4+0] + xv.y*W1c[4*g4+1]
             + xv.z*W1c[4*g4+2] + xv.w*W1c[4*g4+3];
      }
      z[r] = acc;
    }

    // ---- D: attn[k][j] = xc[k] . xb[j]
    {
      const int dk = t >> 4, dj = t & 15;
      float a = 0.f;
#pragma unroll
      for (int f4 = 0; f4 < 16; ++f4) {
        float4 cv = *(const float4*)&xc[dk][4*f4];
        float4 bv = *(const float4*)&xb[dj][4*f4];
        a += cv.x*bv.x + cv.y*bv.y + cv.z*bv.z + cv.w*bv.w;
      }
      attn[dk][dj] = a;
    }

    // ---- C: LN-L2 backward -> gZ
#pragma unroll
    for (int r = 0; r < 4; ++r) {
      const int k = w*4 + r;
      float zz = z[r];
      float mu = wave_sum64(zz) * (1.f/F_);
      float d  = zz - mu;
      float var = wave_sum64(d*d) * (1.f/F_);
      float istd = rsqrtf(var + EPS_);
      float xh = d * istd;
      float gy = (gamr*xh + betr - (xa[k][lane] - xb[k][lane])) * gamr;
      float sgy   = wave_sum64(gy);
      float sgyxh = wave_sum64(gy*xh);
      gZ[k][lane] = (F_*gy - sgy - xh*sgyxh) * (istd * (1.f/F_));
    }
    __syncthreads();                       // #2

    float gzr[K_];
#pragma unroll
    for (int j = 0; j < K_; ++j) gzr[j] = gZ[j][lane];

    // ---- E: Z1_bar rows k=w*4+r
    float zb[4];
#pragma unroll
    for (int r = 0; r < 4; ++r) {
      const int k = w*4 + r;
      float acc = 0.f;
#pragma unroll
      for (int g4 = 0; g4 < 16; ++g4) {
        float4 cv = *(const float4*)&xc[k][4*g4];
        acc += cv.x*W1c[4*g4+0] + cv.y*W1c[4*g4+1]
             + cv.z*W1c[4*g4+2] + cv.w*W1c[4*g4+3];
      }
      float cum = 0.f, ag = 0.f;
#pragma unroll
      for (int j = 0; j < K_; ++j) {
        if (j <= k) { cum += gzr[j]; ag += attn[k][j]*gzr[j]; }
      }
      float bb = b1r - covr[r]*cum;
      zb[r] = acc - covr[r]*ag + bb;
      if (k == K_-1) b1b15[lane] = bb;
    }

    // ---- G: out = xc + LN(Z1_bar) -> OF (f16)
#pragma unroll
    for (int r = 0; r < 4; ++r) {
      const int k = w*4 + r;
      float zz = zb[r];
      float mu = wave_sum64(zz) * (1.f/F_);
      float d  = zz - mu;
      float var = wave_sum64(d*d) * (1.f/F_);
      float istd = rsqrtf(var + EPS_);
      float xh = d * istd;
      OF[obase + (size_t)(n*K_ + k)*C_] = (_Float16)(xc[k][lane] + gamr*xh + betr);
    }

    // ---- F: delta[g][lane] = sum_k xb[k][g]*gZ[k][lane]; wave w rows w*16..+15
    {
      float dl[16];
#pragma unroll
      for (int i = 0; i < 16; ++i) dl[i] = 0.f;
#pragma unroll
      for (int k = 0; k < K_; ++k) {
        const float gk = gzr[k];
#pragma unroll
        for (int q = 0; q < 4; ++q) {
          float4 bv = *(const float4*)&xb[k][w*16 + 4*q];
          dl[4*q+0] += bv.x*gk; dl[4*q+1] += bv.y*gk;
          dl[4*q+2] += bv.z*gk; dl[4*q+3] += bv.w*gk;
        }
      }
#pragma unroll
      for (int i = 0; i < 16; ++i) delta[w*16 + i][lane] = dl[i];
    }
    __syncthreads();                       // #3

    {
      const float c15 = cov15;
#pragma unroll
      for (int g = 0; g < F_; ++g) W1c[g] -= c15 * delta[g][lane];
      b1r = b1b15[lane];
    }
#pragma unroll
    for (int r = 0; r < 4; ++r) covr[r] = covn[r];
    cov15 = cov15n;
  }
}

extern "C" void kernel_launch(void* const* d_in, const int* in_sizes, int n_in,
                              void* d_out, int out_size, void* d_ws, size_t ws_size,
                              hipStream_t stream)
{
  const float* hid   = (const float*)d_in[0];
  const float* q_w   = (const float*)d_in[1];
  const float* k_w   = (const float*)d_in[2];
  const float* v_w   = (const float*)d_in[3];
  const float* o_w   = (const float*)d_in[4];
  const float* lin_w = (const float*)d_in[5];
  const float* lin_b = (const float*)d_in[6];
  const float* ln_w  = (const float*)d_in[7];
  const float* ln_b  = (const float*)d_in[8];
  const float* W1    = (const float*)d_in[9];
  const float* b1    = (const float*)d_in[10];
  float* out = (float*)d_out;

  const size_t BLC = (size_t)B_ * L_ * C_;      // 33.55M elems
  const size_t CC  = (size_t)C_ * C_;           // 4.19M
  _Float16* HF = (_Float16*)d_ws;               // hid f16; later reused as scan output OF
  _Float16* WF = HF + BLC;                      // weight f16 (reused per GEMM)
  _Float16* KF = WF + CC;
  _Float16* VF = KF + BLC;
  float*    CO = (float*)(VF + BLC);            // B*NH*L fp32
  _Float16* QF = (_Float16*)d_out;              // Q f16 in d_out's first half (dead before final GEMM)

  const int M = B_ * L_, N = C_, Kd = C_;
  dim3 gg(N / TN, M / TM);
  const int n8h = (int)(BLC / 8);
  const int n8w = (int)(CC / 8);

  cast_f16<<<(n8h+255)/256, 256, 0, stream>>>(hid, HF, n8h);
  cast_f16<<<(n8w+255)/256, 256, 0, stream>>>(q_w, WF, n8w);
  gemm_f16<_Float16><<<gg, 256, 0, stream>>>(HF, WF, QF, M, N, Kd);
  cast_f16<<<(n8w+255)/256, 256, 0, stream>>>(k_w, WF, n8w);
  gemm_f16<_Float16><<<gg, 256, 0, stream>>>(HF, WF, KF, M, N, Kd);
  cast_f16<<<(n8w+255)/256, 256, 0, stream>>>(v_w, WF, n8w);
  gemm_f16<_Float16><<<gg, 256, 0, stream>>>(HF, WF, VF, M, N, Kd);
  ilr_kernel<<<M / 16, 256, 0, stream>>>(hid, lin_w, lin_b, CO);
  scan_kernel<<<B_ * NH_, 256, 0, stream>>>(QF, KF, VF, CO, W1, b1, ln_w, ln_b, HF);
  cast_f16<<<(n8w+255)/256, 256, 0, stream>>>(o_w, WF, n8w);
  gemm_f16<float><<<gg, 256, 0, stream>>>(HF, WF, out, M, N, Kd);
}

// Round 6
// 1925.382 us; speedup vs baseline: 5.8561x; 1.6630x over previous
//
#include <hip/hip_runtime.h>
#include <hip/hip_bf16.h>

#define B_ 4
#define L_ 4096
#define C_ 2048
#define NH_ 32
#define K_ 16
#define F_ 64
#define NC_ 256
#define EPS_ 1e-6f

typedef _Float16 half8 __attribute__((ext_vector_type(8)));
typedef _Float16 half4 __attribute__((ext_vector_type(4)));
typedef float f32x4 __attribute__((ext_vector_type(4)));

__device__ __forceinline__ float wave_sum64(float v) {
#pragma unroll
  for (int o = 32; o > 0; o >>= 1) v += __shfl_xor(v, o, 64);
  return v;
}

// sum over 16-lane group (lanes sharing lane>>4)
__device__ __forceinline__ float red16(float v) {
  v += __shfl_xor(v, 1, 64);
  v += __shfl_xor(v, 2, 64);
  v += __shfl_xor(v, 4, 64);
  v += __shfl_xor(v, 8, 64);
  return v;
}

__device__ __forceinline__ void gl_lds16(const _Float16* g, _Float16* l) {
  __builtin_amdgcn_global_load_lds(
      (const __attribute__((address_space(1))) void*)g,
      (__attribute__((address_space(3))) void*)l, 16, 0, 0);
}

// ---------------- cast fp32 -> f16, 8 elems/thread ----------------
__global__ __launch_bounds__(256) void cast_f16(const float* __restrict__ in,
                                                _Float16* __restrict__ out, int n8) {
  int i = blockIdx.x * 256 + threadIdx.x;
  if (i >= n8) return;
  const float4* ip = (const float4*)in;
  float4 a = ip[2*i], b = ip[2*i+1];
  half8 o;
  o[0]=(_Float16)a.x; o[1]=(_Float16)a.y; o[2]=(_Float16)a.z; o[3]=(_Float16)a.w;
  o[4]=(_Float16)b.x; o[5]=(_Float16)b.y; o[6]=(_Float16)b.z; o[7]=(_Float16)b.w;
  ((half8*)out)[i] = o;
}

// ---------------- f16 MFMA GEMM (m97 structure) ----------------
#define TM 128
#define TN 128
#define TK 32

template<typename OT>
__global__ __launch_bounds__(256) void gemm_f16(
    const _Float16* __restrict__ A, const _Float16* __restrict__ Bm,
    OT* __restrict__ C, int M, int N, int Kd)
{
  __shared__ __align__(16) _Float16 As[TM*TK];
  __shared__ __align__(16) _Float16 Bs[TN*TK];
  const int t = threadIdx.x;
  const int lane = t & 63;
  const int bn = blockIdx.x, bm = blockIdx.y;
  const int w = t >> 6;
  const int wm = (w >> 1) * 64, wn = (w & 1) * 64;

  const _Float16* ga1 = A  + ((long)(bm*TM +      (t>>2)))*Kd + (t&3)*8;
  const _Float16* ga2 = A  + ((long)(bm*TM + 64 + (t>>2)))*Kd + (t&3)*8;
  const _Float16* gb1 = Bm + ((long)(bn*TN +      (t>>2)))*Kd + (t&3)*8;
  const _Float16* gb2 = Bm + ((long)(bn*TN + 64 + (t>>2)))*Kd + (t&3)*8;
  _Float16* la1 = As + (size_t)t*8;
  _Float16* la2 = As + (size_t)(t+256)*8;
  _Float16* lb1 = Bs + (size_t)t*8;
  _Float16* lb2 = Bs + (size_t)(t+256)*8;

  f32x4 acc[4][4];
#pragma unroll
  for (int i = 0; i < 4; ++i)
#pragma unroll
    for (int j = 0; j < 4; ++j) acc[i][j] = (f32x4){0.f,0.f,0.f,0.f};

  for (int k0 = 0; k0 < Kd; k0 += TK) {
    __syncthreads();
    gl_lds16(ga1 + k0, la1);
    gl_lds16(ga2 + k0, la2);
    gl_lds16(gb1 + k0, lb1);
    gl_lds16(gb2 + k0, lb2);
    __syncthreads();
    half8 af[4], bf[4];
#pragma unroll
    for (int i = 0; i < 4; ++i)
      af[i] = *(const half8*)(As + (size_t)(wm + i*16 + (lane&15))*TK + (lane>>4)*8);
#pragma unroll
    for (int j = 0; j < 4; ++j)
      bf[j] = *(const half8*)(Bs + (size_t)(wn + j*16 + (lane&15))*TK + (lane>>4)*8);
#pragma unroll
    for (int i = 0; i < 4; ++i)
#pragma unroll
      for (int j = 0; j < 4; ++j)
        acc[i][j] = __builtin_amdgcn_mfma_f32_16x16x32_f16(af[i], bf[j], acc[i][j], 0, 0, 0);
  }

  const int cr = (lane >> 4) * 4, cc = lane & 15;
#pragma unroll
  for (int i = 0; i < 4; ++i)
#pragma unroll
    for (int j = 0; j < 4; ++j)
#pragma unroll
      for (int r = 0; r < 4; ++r) {
        long row = (long)bm*TM + wm + i*16 + cr + r;
        long col = (long)bn*TN + wn + j*16 + cc;
        C[row*(long)N + col] = (OT)acc[i][j][r];
      }
}

// ---------------- ilr / coeff (fp32) ----------------
__global__ __launch_bounds__(256) void ilr_kernel(
    const float* __restrict__ hid, const float* __restrict__ lin_w,
    const float* __restrict__ lin_b, float* __restrict__ coeff)
{
  const int t = threadIdx.x;
  const int lane = t & 63;
  const int w = t >> 6;
  const int row0 = blockIdx.x * 16 + w * 4;

  float4 hv[4][8];
#pragma unroll
  for (int r = 0; r < 4; ++r) {
    const float* hp = hid + (size_t)(row0 + r) * C_;
#pragma unroll
    for (int i = 0; i < 8; ++i) hv[r][i] = *(const float4*)(hp + i*256 + lane*4);
  }
  float res[4] = {0.f,0.f,0.f,0.f};
  for (int h = 0; h < NH_; ++h) {
    const float* wp = lin_w + (size_t)h * C_;
    float s[4] = {0.f,0.f,0.f,0.f};
#pragma unroll
    for (int i = 0; i < 8; ++i) {
      float4 wv = *(const float4*)(wp + i*256 + lane*4);
#pragma unroll
      for (int r = 0; r < 4; ++r)
        s[r] += hv[r][i].x*wv.x + hv[r][i].y*wv.y + hv[r][i].z*wv.z + hv[r][i].w*wv.w;
    }
#pragma unroll
    for (int o = 32; o > 0; o >>= 1)
#pragma unroll
      for (int r = 0; r < 4; ++r) s[r] += __shfl_xor(s[r], o, 64);
    if (lane == h) { res[0]=s[0]; res[1]=s[1]; res[2]=s[2]; res[3]=s[3]; }
  }
  if (lane < NH_) {
    float lb = lin_b[lane];
#pragma unroll
    for (int r = 0; r < 4; ++r) {
      int row = row0 + r;
      int b = row >> 12;
      int li = row & (L_ - 1);
      int k = li & (K_ - 1);
      float x = res[r] + lb;
      float sp = (x > 20.f) ? x : log1pf(expf(x));
      float v = (1.0f / (float)(k + 1)) * sp * (1.0f / (float)F_);
      coeff[((size_t)(b * NH_ + lane)) * L_ + li] = v;
    }
  }
}

// ---------------- TTT scan v3: 1 wave per (b,h); MFMA; no LDS ----------------
// Layouts (16x16x16 MFMA, q=lane>>4, ln=lane&15):
//   A-frag: lane holds A[ln][4q+j]          (j=0..3)
//   B-frag: lane holds B[4q+j][ln]
//   C/D:    lane holds C[4q+r][ln]          -> identical structure to B-frag!
// W1 (64x64) = 4x4 tiles W1t[kt][t], each in B-frag layout:
//   W1t[kt][t][j] = W1[16kt+4q+j][16t+ln]
// Delta = xb^T@gZ computed by MFMA lands tile-exactly in this layout.

struct Ck {
  half4 xbA[4], xcA[4];   // A-frags of xb, xc
  float tg[4][4];         // (xa - xb) at C/D positions (t, r)
  _Float16 xcs[4][4];     // xc at C/D positions
  half4 xbT[4];           // A-frags of xb^T per m-tile
  float co4[4], co15;
};

__device__ __forceinline__ void load_ck(
    Ck& c, const _Float16* Q, const _Float16* Kp, const _Float16* V,
    const float* co, size_t rowbase, int hoff, size_t cobase, int n, int q, int ln)
{
#pragma unroll
  for (int kt = 0; kt < 4; ++kt) {
    size_t idx = (rowbase + ln) * C_ + hoff + 16*kt + 4*q;
    c.xbA[kt] = *(const half4*)(Kp + idx);
    c.xcA[kt] = *(const half4*)(Q  + idx);
  }
#pragma unroll
  for (int t = 0; t < 4; ++t)
#pragma unroll
    for (int r = 0; r < 4; ++r) {
      size_t idx = (rowbase + 4*q + r) * C_ + hoff + 16*t + ln;
      c.tg[t][r]  = (float)V[idx] - (float)Kp[idx];
      c.xcs[t][r] = Q[idx];
    }
#pragma unroll
  for (int mt = 0; mt < 4; ++mt) {
    half4 v;
#pragma unroll
    for (int j = 0; j < 4; ++j)
      v[j] = Kp[(rowbase + 4*q + j) * C_ + hoff + 16*mt + ln];
    c.xbT[mt] = v;
  }
#pragma unroll
  for (int r = 0; r < 4; ++r) c.co4[r] = co[cobase + (size_t)n*K_ + 4*q + r];
  c.co15 = co[cobase + (size_t)n*K_ + 15];
}

__global__ __launch_bounds__(64, 1) void scan_kernel(
    const _Float16* __restrict__ Q, const _Float16* __restrict__ Kp,
    const _Float16* __restrict__ V,
    const float* __restrict__ coeff, const float* __restrict__ W1g, const float* __restrict__ b1g,
    const float* __restrict__ ln_w, const float* __restrict__ ln_b,
    _Float16* __restrict__ OF)
{
  const int bh = blockIdx.x;
  const int b = bh >> 5, h = bh & 31;
  const int lane = threadIdx.x;
  const int q = lane >> 4, ln = lane & 15;
  const int hoff = h * F_;
  const size_t cobase = (size_t)bh * L_;
  const size_t brow = (size_t)b * L_;

  // persistent state
  float W1t[4][4][4];
#pragma unroll
  for (int kt = 0; kt < 4; ++kt)
#pragma unroll
    for (int t = 0; t < 4; ++t)
#pragma unroll
      for (int j = 0; j < 4; ++j)
        W1t[kt][t][j] = W1g[(size_t)h*F_*F_ + (size_t)(16*kt + 4*q + j)*F_ + 16*t + ln];
  float b1r[4], gamt[4], bett[4];
#pragma unroll
  for (int t = 0; t < 4; ++t) {
    b1r[t]  = b1g[hoff + 16*t + ln];
    gamt[t] = ln_w[hoff + 16*t + ln];
    bett[t] = ln_b[hoff + 16*t + ln];
  }
  half4 maskA;
#pragma unroll
  for (int j = 0; j < 4; ++j) maskA[j] = (_Float16)((4*q + j <= ln) ? 1.f : 0.f);
  const f32x4 zf4 = (f32x4){0.f, 0.f, 0.f, 0.f};

  auto body = [&](const Ck& ck, int n) {
    const size_t rowbase = brow + (size_t)n * K_;
    // 1. hi/lo split of W1
    half4 Whi[4][4], Wlo[4][4];
#pragma unroll
    for (int kt = 0; kt < 4; ++kt)
#pragma unroll
      for (int t = 0; t < 4; ++t) {
        half4 hv, lv;
#pragma unroll
        for (int j = 0; j < 4; ++j) {
          float wv = W1t[kt][t][j];
          _Float16 hi = (_Float16)wv;
          hv[j] = hi;
          lv[j] = (_Float16)(wv - (float)hi);
        }
        Whi[kt][t] = hv; Wlo[kt][t] = lv;
      }

    // 2. z = xb@W1 + b1
    f32x4 za[4];
#pragma unroll
    for (int t = 0; t < 4; ++t) {
      za[t] = (f32x4){b1r[t], b1r[t], b1r[t], b1r[t]};
#pragma unroll
      for (int kt = 0; kt < 4; ++kt) {
        za[t] = __builtin_amdgcn_mfma_f32_16x16x16f16(ck.xbA[kt], Whi[kt][t], za[t], 0, 0, 0);
        za[t] = __builtin_amdgcn_mfma_f32_16x16x16f16(ck.xbA[kt], Wlo[kt][t], za[t], 0, 0, 0);
      }
    }

    // 3. attnT = xb@xc^T, masked -> f16 A-frag of attn
    f32x4 at = zf4;
#pragma unroll
    for (int kt = 0; kt < 4; ++kt)
      at = __builtin_amdgcn_mfma_f32_16x16x16f16(ck.xbA[kt], ck.xcA[kt], at, 0, 0, 0);
    half4 atf;
#pragma unroll
    for (int r = 0; r < 4; ++r) atf[r] = (_Float16)((4*q + r <= ln) ? at[r] : 0.f);

    // 4. LN-L2 backward -> gZ (f16, C/D layout == B-frag layout)
    half4 gzf[4];
#pragma unroll
    for (int r = 0; r < 4; ++r) {
      float s = za[0][r] + za[1][r] + za[2][r] + za[3][r];
      float mu = red16(s) * (1.f/F_);
      float dv[4], v2 = 0.f;
#pragma unroll
      for (int t = 0; t < 4; ++t) { dv[t] = za[t][r] - mu; v2 += dv[t]*dv[t]; }
      float istd = rsqrtf(red16(v2) * (1.f/F_) + EPS_);
      float xht[4], gy[4], sg = 0.f, sx = 0.f;
#pragma unroll
      for (int t = 0; t < 4; ++t) {
        xht[t] = dv[t] * istd;
        gy[t] = (gamt[t]*xht[t] + bett[t] - ck.tg[t][r]) * gamt[t];
        sg += gy[t]; sx += gy[t]*xht[t];
      }
      sg = red16(sg); sx = red16(sx);
      const float sc = istd * (1.f/F_);
#pragma unroll
      for (int t = 0; t < 4; ++t)
        gzf[t][r] = (_Float16)((F_*gy[t] - sg - xht[t]*sx) * sc);
    }

    // 5. cum = maskL@gZ ; ag = attn@gZ
    f32x4 cum[4], ag[4];
#pragma unroll
    for (int t = 0; t < 4; ++t) {
      cum[t] = __builtin_amdgcn_mfma_f32_16x16x16f16(maskA, gzf[t], zf4, 0, 0, 0);
      ag[t]  = __builtin_amdgcn_mfma_f32_16x16x16f16(atf,   gzf[t], zf4, 0, 0, 0);
    }

    // 6. zb = xc@W1 + b1 - co*(ag + cum)
    f32x4 zbv[4];
#pragma unroll
    for (int t = 0; t < 4; ++t) {
      zbv[t] = zf4;
#pragma unroll
      for (int kt = 0; kt < 4; ++kt) {
        zbv[t] = __builtin_amdgcn_mfma_f32_16x16x16f16(ck.xcA[kt], Whi[kt][t], zbv[t], 0, 0, 0);
        zbv[t] = __builtin_amdgcn_mfma_f32_16x16x16f16(ck.xcA[kt], Wlo[kt][t], zbv[t], 0, 0, 0);
      }
    }
    float zbf[4][4];
#pragma unroll
    for (int t = 0; t < 4; ++t)
#pragma unroll
      for (int r = 0; r < 4; ++r)
        zbf[t][r] = zbv[t][r] + b1r[t] - ck.co4[r]*(ag[t][r] + cum[t][r]);

    // 7. out = xc + LN(zb), scalar f16 stores
#pragma unroll
    for (int r = 0; r < 4; ++r) {
      float s = zbf[0][r] + zbf[1][r] + zbf[2][r] + zbf[3][r];
      float mu = red16(s) * (1.f/F_);
      float dv[4], v2 = 0.f;
#pragma unroll
      for (int t = 0; t < 4; ++t) { dv[t] = zbf[t][r] - mu; v2 += dv[t]*dv[t]; }
      float istd = rsqrtf(red16(v2) * (1.f/F_) + EPS_);
#pragma unroll
      for (int t = 0; t < 4; ++t) {
        float ov = (float)ck.xcs[t][r] + gamt[t]*(dv[t]*istd) + bett[t];
        OF[(rowbase + 4*q + r) * C_ + hoff + 16*t + ln] = (_Float16)ov;
      }
    }

    // 8. b1 <- row 15 of b1_bar (lives on lanes q==3, reg r=3)
#pragma unroll
    for (int t = 0; t < 4; ++t) {
      float tmp = b1r[t] - ck.co15 * cum[t][3];
      b1r[t] = __shfl(tmp, 48 + ln, 64);
    }

    // 9. W1 -= co15 * xb^T@gZ   (delta C/D tile == W1 tile layout)
#pragma unroll
    for (int mt = 0; mt < 4; ++mt)
#pragma unroll
      for (int t = 0; t < 4; ++t) {
        f32x4 d = __builtin_amdgcn_mfma_f32_16x16x16f16(ck.xbT[mt], gzf[t], zf4, 0, 0, 0);
#pragma unroll
        for (int r = 0; r < 4; ++r) W1t[mt][t][r] -= ck.co15 * d[r];
      }
  };

  Ck cka, ckb;
  load_ck(cka, Q, Kp, V, coeff, brow, hoff, cobase, 0, q, ln);
  for (int n = 0; n < NC_; n += 2) {
    load_ck(ckb, Q, Kp, V, coeff, brow + (size_t)(n+1)*K_, hoff, cobase, n+1, q, ln);
    body(cka, n);
    int np = (n + 2 < NC_) ? n + 2 : NC_ - 1;
    load_ck(cka, Q, Kp, V, coeff, brow + (size_t)np*K_, hoff, cobase, np, q, ln);
    body(ckb, n + 1);
  }
}

extern "C" void kernel_launch(void* const* d_in, const int* in_sizes, int n_in,
                              void* d_out, int out_size, void* d_ws, size_t ws_size,
                              hipStream_t stream)
{
  const float* hid   = (const float*)d_in[0];
  const float* q_w   = (const float*)d_in[1];
  const float* k_w   = (const float*)d_in[2];
  const float* v_w   = (const float*)d_in[3];
  const float* o_w   = (const float*)d_in[4];
  const float* lin_w = (const float*)d_in[5];
  const float* lin_b = (const float*)d_in[6];
  const float* ln_w  = (const float*)d_in[7];
  const float* ln_b  = (const float*)d_in[8];
  const float* W1    = (const float*)d_in[9];
  const float* b1    = (const float*)d_in[10];
  float* out = (float*)d_out;

  const size_t BLC = (size_t)B_ * L_ * C_;
  const size_t CC  = (size_t)C_ * C_;
  _Float16* HF = (_Float16*)d_ws;               // hid f16; later scan output
  _Float16* WF = HF + BLC;
  _Float16* KF = WF + CC;
  _Float16* VF = KF + BLC;
  float*    CO = (float*)(VF + BLC);
  _Float16* QF = (_Float16*)d_out;              // Q f16 in d_out (dead before final GEMM)

  const int M = B_ * L_, N = C_, Kd = C_;
  dim3 gg(N / TN, M / TM);
  const int n8h = (int)(BLC / 8);
  const int n8w = (int)(CC / 8);

  cast_f16<<<(n8h+255)/256, 256, 0, stream>>>(hid, HF, n8h);
  cast_f16<<<(n8w+255)/256, 256, 0, stream>>>(q_w, WF, n8w);
  gemm_f16<_Float16><<<gg, 256, 0, stream>>>(HF, WF, QF, M, N, Kd);
  cast_f16<<<(n8w+255)/256, 256, 0, stream>>>(k_w, WF, n8w);
  gemm_f16<_Float16><<<gg, 256, 0, stream>>>(HF, WF, KF, M, N, Kd);
  cast_f16<<<(n8w+255)/256, 256, 0, stream>>>(v_w, WF, n8w);
  gemm_f16<_Float16><<<gg, 256, 0, stream>>>(HF, WF, VF, M, N, Kd);
  ilr_kernel<<<M / 16, 256, 0, stream>>>(hid, lin_w, lin_b, CO);
  scan_kernel<<<B_ * NH_, 64, 0, stream>>>(QF, KF, VF, CO, W1, b1, ln_w, ln_b, HF);
  cast_f16<<<(n8w+255)/256, 256, 0, stream>>>(o_w, WF, n8w);
  gemm_f16<float><<<gg, 256, 0, stream>>>(HF, WF, out, M, N, Kd);
}

// Round 7
// 1769.874 us; speedup vs baseline: 6.3706x; 1.0879x over previous
//
#include <hip/hip_runtime.h>
#include <hip/hip_bf16.h>

#define B_ 4
#define L_ 4096
#define C_ 2048
#define NH_ 32
#define K_ 16
#define F_ 64
#define NC_ 256
#define EPS_ 1e-6f

typedef _Float16 half8 __attribute__((ext_vector_type(8)));
typedef _Float16 half4 __attribute__((ext_vector_type(4)));
typedef float f32x4 __attribute__((ext_vector_type(4)));

// sum over 16-lane group (lanes sharing lane>>4)
__device__ __forceinline__ float red16(float v) {
  v += __shfl_xor(v, 1, 64);
  v += __shfl_xor(v, 2, 64);
  v += __shfl_xor(v, 4, 64);
  v += __shfl_xor(v, 8, 64);
  return v;
}

__device__ __forceinline__ void gl_lds16(const _Float16* g, _Float16* l) {
  __builtin_amdgcn_global_load_lds(
      (const __attribute__((address_space(1))) void*)g,
      (__attribute__((address_space(3))) void*)l, 16, 0, 0);
}

// ---------------- cast fp32 -> f16, 8 elems/thread ----------------
__global__ __launch_bounds__(256) void cast_f16(const float* __restrict__ in,
                                                _Float16* __restrict__ out, int n8) {
  int i = blockIdx.x * 256 + threadIdx.x;
  if (i >= n8) return;
  const float4* ip = (const float4*)in;
  float4 a = ip[2*i], b = ip[2*i+1];
  half8 o;
  o[0]=(_Float16)a.x; o[1]=(_Float16)a.y; o[2]=(_Float16)a.z; o[3]=(_Float16)a.w;
  o[4]=(_Float16)b.x; o[5]=(_Float16)b.y; o[6]=(_Float16)b.z; o[7]=(_Float16)b.w;
  ((half8*)out)[i] = o;
}

// ---------------- f16 MFMA GEMM (m97 structure) ----------------
#define TM 128
#define TN 128
#define TK 32

template<typename OT>
__global__ __launch_bounds__(256) void gemm_f16(
    const _Float16* __restrict__ A, const _Float16* __restrict__ Bm,
    OT* __restrict__ C, int M, int N, int Kd)
{
  __shared__ __align__(16) _Float16 As[TM*TK];
  __shared__ __align__(16) _Float16 Bs[TN*TK];
  const int t = threadIdx.x;
  const int lane = t & 63;
  const int bn = blockIdx.x, bm = blockIdx.y;
  const int w = t >> 6;
  const int wm = (w >> 1) * 64, wn = (w & 1) * 64;

  const _Float16* ga1 = A  + ((long)(bm*TM +      (t>>2)))*Kd + (t&3)*8;
  const _Float16* ga2 = A  + ((long)(bm*TM + 64 + (t>>2)))*Kd + (t&3)*8;
  const _Float16* gb1 = Bm + ((long)(bn*TN +      (t>>2)))*Kd + (t&3)*8;
  const _Float16* gb2 = Bm + ((long)(bn*TN + 64 + (t>>2)))*Kd + (t&3)*8;
  _Float16* la1 = As + (size_t)t*8;
  _Float16* la2 = As + (size_t)(t+256)*8;
  _Float16* lb1 = Bs + (size_t)t*8;
  _Float16* lb2 = Bs + (size_t)(t+256)*8;

  f32x4 acc[4][4];
#pragma unroll
  for (int i = 0; i < 4; ++i)
#pragma unroll
    for (int j = 0; j < 4; ++j) acc[i][j] = (f32x4){0.f,0.f,0.f,0.f};

  for (int k0 = 0; k0 < Kd; k0 += TK) {
    __syncthreads();
    gl_lds16(ga1 + k0, la1);
    gl_lds16(ga2 + k0, la2);
    gl_lds16(gb1 + k0, lb1);
    gl_lds16(gb2 + k0, lb2);
    __syncthreads();
    half8 af[4], bf[4];
#pragma unroll
    for (int i = 0; i < 4; ++i)
      af[i] = *(const half8*)(As + (size_t)(wm + i*16 + (lane&15))*TK + (lane>>4)*8);
#pragma unroll
    for (int j = 0; j < 4; ++j)
      bf[j] = *(const half8*)(Bs + (size_t)(wn + j*16 + (lane&15))*TK + (lane>>4)*8);
#pragma unroll
    for (int i = 0; i < 4; ++i)
#pragma unroll
      for (int j = 0; j < 4; ++j)
        acc[i][j] = __builtin_amdgcn_mfma_f32_16x16x32_f16(af[i], bf[j], acc[i][j], 0, 0, 0);
  }

  const int cr = (lane >> 4) * 4, cc = lane & 15;
#pragma unroll
  for (int i = 0; i < 4; ++i)
#pragma unroll
    for (int j = 0; j < 4; ++j)
#pragma unroll
      for (int r = 0; r < 4; ++r) {
        long row = (long)bm*TM + wm + i*16 + cr + r;
        long col = (long)bn*TN + wn + j*16 + cc;
        C[row*(long)N + col] = (OT)acc[i][j][r];
      }
}

// ---------------- ilr / coeff (fp32) ----------------
__global__ __launch_bounds__(256) void ilr_kernel(
    const float* __restrict__ hid, const float* __restrict__ lin_w,
    const float* __restrict__ lin_b, float* __restrict__ coeff)
{
  const int t = threadIdx.x;
  const int lane = t & 63;
  const int w = t >> 6;
  const int row0 = blockIdx.x * 16 + w * 4;

  float4 hv[4][8];
#pragma unroll
  for (int r = 0; r < 4; ++r) {
    const float* hp = hid + (size_t)(row0 + r) * C_;
#pragma unroll
    for (int i = 0; i < 8; ++i) hv[r][i] = *(const float4*)(hp + i*256 + lane*4);
  }
  float res[4] = {0.f,0.f,0.f,0.f};
  for (int h = 0; h < NH_; ++h) {
    const float* wp = lin_w + (size_t)h * C_;
    float s[4] = {0.f,0.f,0.f,0.f};
#pragma unroll
    for (int i = 0; i < 8; ++i) {
      float4 wv = *(const float4*)(wp + i*256 + lane*4);
#pragma unroll
      for (int r = 0; r < 4; ++r)
        s[r] += hv[r][i].x*wv.x + hv[r][i].y*wv.y + hv[r][i].z*wv.z + hv[r][i].w*wv.w;
    }
#pragma unroll
    for (int o = 32; o > 0; o >>= 1)
#pragma unroll
      for (int r = 0; r < 4; ++r) s[r] += __shfl_xor(s[r], o, 64);
    if (lane == h) { res[0]=s[0]; res[1]=s[1]; res[2]=s[2]; res[3]=s[3]; }
  }
  if (lane < NH_) {
    float lb = lin_b[lane];
#pragma unroll
    for (int r = 0; r < 4; ++r) {
      int row = row0 + r;
      int b = row >> 12;
      int li = row & (L_ - 1);
      int k = li & (K_ - 1);
      float x = res[r] + lb;
      float sp = (x > 20.f) ? x : log1pf(expf(x));
      float v = (1.0f / (float)(k + 1)) * sp * (1.0f / (float)F_);
      coeff[((size_t)(b * NH_ + lane)) * L_ + li] = v;
    }
  }
}

// ---------------- TTT scan v4: all-register MFMA, shorter chains ----------
// Layouts (16x16x16 MFMA, q=lane>>4, ln=lane&15):
//   A-frag: lane holds A[ln][4q+j];  B-frag: B[4q+j][ln];  C/D: C[4q+r][ln].
// Identity-transpose: (M@I) relays A-frag of M into C/D positions.
// Reinterpreting xb's C/D as an A-frag yields the A-frag of xb^T.
// W1 = Whi (f16, persistent) + Wlo (f32 residual, absorbs all updates).

struct Ck {
  half4 xbA[4], xcA[4], xaA[4];  // A-frags per feature-tile
  float co4[4], co15;
};

__device__ __forceinline__ void load_ck(
    Ck& c, const _Float16* Q, const _Float16* Kp, const _Float16* V,
    const float* co, size_t rowbase, int hoff, size_t cobase, int n, int q, int ln)
{
#pragma unroll
  for (int kt = 0; kt < 4; ++kt) {
    size_t idx = (rowbase + ln) * C_ + hoff + 16*kt + 4*q;
    c.xbA[kt] = *(const half4*)(Kp + idx);
    c.xcA[kt] = *(const half4*)(Q  + idx);
    c.xaA[kt] = *(const half4*)(V  + idx);
  }
#pragma unroll
  for (int r = 0; r < 4; ++r) c.co4[r] = co[cobase + (size_t)n*K_ + 4*q + r];
  c.co15 = co[cobase + (size_t)n*K_ + 15];
}

__global__ __launch_bounds__(64, 1) void scan_kernel(
    const _Float16* __restrict__ Q, const _Float16* __restrict__ Kp,
    const _Float16* __restrict__ V,
    const float* __restrict__ coeff, const float* __restrict__ W1g, const float* __restrict__ b1g,
    const float* __restrict__ ln_w, const float* __restrict__ ln_b,
    _Float16* __restrict__ OF)
{
  const int bh = blockIdx.x;
  const int b = bh >> 5, h = bh & 31;
  const int lane = threadIdx.x;
  const int q = lane >> 4, ln = lane & 15;
  const int hoff = h * F_;
  const size_t cobase = (size_t)bh * L_;
  const size_t brow = (size_t)b * L_;

  // persistent W1 state: f16 hi (never re-split) + f32 lo residual
  half4 Whi[4][4];
  f32x4 Wlo[4][4];
#pragma unroll
  for (int kt = 0; kt < 4; ++kt)
#pragma unroll
    for (int t = 0; t < 4; ++t) {
      half4 hv; f32x4 lv;
#pragma unroll
      for (int j = 0; j < 4; ++j) {
        float wv = W1g[(size_t)h*F_*F_ + (size_t)(16*kt + 4*q + j)*F_ + 16*t + ln];
        _Float16 hi = (_Float16)wv;
        hv[j] = hi; lv[j] = wv - (float)hi;
      }
      Whi[kt][t] = hv; Wlo[kt][t] = lv;
    }
  float b1r[4], gamt[4], bett[4];
#pragma unroll
  for (int t = 0; t < 4; ++t) {
    b1r[t]  = b1g[hoff + 16*t + ln];
    gamt[t] = ln_w[hoff + 16*t + ln];
    bett[t] = ln_b[hoff + 16*t + ln];
  }
  half4 maskA, maskI;
#pragma unroll
  for (int j = 0; j < 4; ++j) {
    maskA[j] = (_Float16)((4*q + j <= ln) ? 1.f : 0.f);
    maskI[j] = (_Float16)((4*q + j == ln) ? 1.f : 0.f);
  }
  const f32x4 zf4 = (f32x4){0.f, 0.f, 0.f, 0.f};

  auto body = [&](const Ck& ck, int n) {
    const size_t rowbase = brow + (size_t)n * K_;

    // 0. f16 view of the lo residual (64 cvt)
    half4 Wlo16[4][4];
#pragma unroll
    for (int kt = 0; kt < 4; ++kt)
#pragma unroll
      for (int t = 0; t < 4; ++t) {
        half4 lv;
#pragma unroll
        for (int j = 0; j < 4; ++j) lv[j] = (_Float16)Wlo[kt][t][j];
        Wlo16[kt][t] = lv;
      }

    // 0b. identity-transposes: tg=(xa-xb), xcs, xbT into C/D positions
    f32x4 tgD[4], xcsD[4];
    half4 xbT[4];
#pragma unroll
    for (int t = 0; t < 4; ++t) {
      half4 dd = ck.xaA[t] - ck.xbA[t];
      tgD[t]  = __builtin_amdgcn_mfma_f32_16x16x16f16(dd, maskI, zf4, 0, 0, 0);
      xcsD[t] = __builtin_amdgcn_mfma_f32_16x16x16f16(ck.xcA[t], maskI, zf4, 0, 0, 0);
      f32x4 x = __builtin_amdgcn_mfma_f32_16x16x16f16(ck.xbA[t], maskI, zf4, 0, 0, 0);
      half4 v;
#pragma unroll
      for (int r = 0; r < 4; ++r) v[r] = (_Float16)x[r];
      xbT[t] = v;
    }

    // 1. z = xb@W1 + b1 (hi/lo chains split for ILP)
    f32x4 za[4];
#pragma unroll
    for (int t = 0; t < 4; ++t) {
      f32x4 zh = (f32x4){b1r[t], b1r[t], b1r[t], b1r[t]};
      f32x4 zl = zf4;
#pragma unroll
      for (int kt = 0; kt < 4; ++kt) {
        zh = __builtin_amdgcn_mfma_f32_16x16x16f16(ck.xbA[kt], Whi[kt][t],   zh, 0, 0, 0);
        zl = __builtin_amdgcn_mfma_f32_16x16x16f16(ck.xbA[kt], Wlo16[kt][t], zl, 0, 0, 0);
      }
      za[t] = zh + zl;
    }

    // 2. attnT = xb@xc^T (2+2 split), masked -> f16 A-frag of attn
    f32x4 at0 = zf4, at1 = zf4;
    at0 = __builtin_amdgcn_mfma_f32_16x16x16f16(ck.xbA[0], ck.xcA[0], at0, 0, 0, 0);
    at0 = __builtin_amdgcn_mfma_f32_16x16x16f16(ck.xbA[1], ck.xcA[1], at0, 0, 0, 0);
    at1 = __builtin_amdgcn_mfma_f32_16x16x16f16(ck.xbA[2], ck.xcA[2], at1, 0, 0, 0);
    at1 = __builtin_amdgcn_mfma_f32_16x16x16f16(ck.xbA[3], ck.xcA[3], at1, 0, 0, 0);
    f32x4 at = at0 + at1;
    half4 atf;
#pragma unroll
    for (int r = 0; r < 4; ++r) atf[r] = (_Float16)((4*q + r <= ln) ? at[r] : 0.f);

    // 3. LN-L2 backward -> gZ (single-pass mean/var; sg||sx parallel)
    half4 gzf[4];
#pragma unroll
    for (int r = 0; r < 4; ++r) {
      float zr[4], s1 = 0.f, s2 = 0.f;
#pragma unroll
      for (int t = 0; t < 4; ++t) { zr[t] = za[t][r]; s1 += zr[t]; s2 += zr[t]*zr[t]; }
      s1 = red16(s1); s2 = red16(s2);
      float mu = s1 * (1.f/F_);
      float istd = rsqrtf(s2 * (1.f/F_) - mu*mu + EPS_);
      float xh[4], gy[4], sg = 0.f, sx = 0.f;
#pragma unroll
      for (int t = 0; t < 4; ++t) {
        xh[t] = (zr[t] - mu) * istd;
        gy[t] = (gamt[t]*xh[t] + bett[t] - tgD[t][r]) * gamt[t];
        sg += gy[t]; sx += gy[t]*xh[t];
      }
      sg = red16(sg); sx = red16(sx);
      const float sc = istd * (1.f/F_);
#pragma unroll
      for (int t = 0; t < 4; ++t)
        gzf[t][r] = (_Float16)((F_*gy[t] - sg - xh[t]*sx) * sc);
    }

    // 4. cum = maskL@gZ ; ag = attn@gZ
    f32x4 cum[4], ag[4];
#pragma unroll
    for (int t = 0; t < 4; ++t) {
      cum[t] = __builtin_amdgcn_mfma_f32_16x16x16f16(maskA, gzf[t], zf4, 0, 0, 0);
      ag[t]  = __builtin_amdgcn_mfma_f32_16x16x16f16(atf,   gzf[t], zf4, 0, 0, 0);
    }

    // 5. zb = xc@W1 + b1 - co*(ag + cum)
    float zbf[4][4];
#pragma unroll
    for (int t = 0; t < 4; ++t) {
      f32x4 zh = zf4, zl = zf4;
#pragma unroll
      for (int kt = 0; kt < 4; ++kt) {
        zh = __builtin_amdgcn_mfma_f32_16x16x16f16(ck.xcA[kt], Whi[kt][t],   zh, 0, 0, 0);
        zl = __builtin_amdgcn_mfma_f32_16x16x16f16(ck.xcA[kt], Wlo16[kt][t], zl, 0, 0, 0);
      }
      f32x4 s = zh + zl;
#pragma unroll
      for (int r = 0; r < 4; ++r)
        zbf[t][r] = s[r] + b1r[t] - ck.co4[r]*(ag[t][r] + cum[t][r]);
    }

    // 6. out = xc + LN(zb) (single-pass mean/var), scalar f16 stores
#pragma unroll
    for (int r = 0; r < 4; ++r) {
      float zr[4], s1 = 0.f, s2 = 0.f;
#pragma unroll
      for (int t = 0; t < 4; ++t) { zr[t] = zbf[t][r]; s1 += zr[t]; s2 += zr[t]*zr[t]; }
      s1 = red16(s1); s2 = red16(s2);
      float mu = s1 * (1.f/F_);
      float istd = rsqrtf(s2 * (1.f/F_) - mu*mu + EPS_);
#pragma unroll
      for (int t = 0; t < 4; ++t) {
        float ov = xcsD[t][r] + gamt[t]*((zr[t] - mu)*istd) + bett[t];
        OF[(rowbase + 4*q + r) * C_ + hoff + 16*t + ln] = (_Float16)ov;
      }
    }

    // 7. b1 <- row 15 of b1_bar (lanes q==3, reg r=3)
#pragma unroll
    for (int t = 0; t < 4; ++t) {
      float tmp = b1r[t] - ck.co15 * cum[t][3];
      b1r[t] = __shfl(tmp, 48 + ln, 64);
    }

    // 8. W1 residual update: Wlo -= co15 * xb^T@gZ
#pragma unroll
    for (int mt = 0; mt < 4; ++mt)
#pragma unroll
      for (int t = 0; t < 4; ++t) {
        f32x4 d = __builtin_amdgcn_mfma_f32_16x16x16f16(xbT[mt], gzf[t], zf4, 0, 0, 0);
#pragma unroll
        for (int r = 0; r < 4; ++r) Wlo[mt][t][r] -= ck.co15 * d[r];
      }
  };

  Ck cka, ckb;
  load_ck(cka, Q, Kp, V, coeff, brow, hoff, cobase, 0, q, ln);
  for (int n = 0; n < NC_; n += 2) {
    load_ck(ckb, Q, Kp, V, coeff, brow + (size_t)(n+1)*K_, hoff, cobase, n+1, q, ln);
    body(cka, n);
    int np = (n + 2 < NC_) ? n + 2 : NC_ - 1;
    load_ck(cka, Q, Kp, V, coeff, brow + (size_t)np*K_, hoff, cobase, np, q, ln);
    body(ckb, n + 1);
  }
}

extern "C" void kernel_launch(void* const* d_in, const int* in_sizes, int n_in,
                              void* d_out, int out_size, void* d_ws, size_t ws_size,
                              hipStream_t stream)
{
  const float* hid   = (const float*)d_in[0];
  const float* q_w   = (const float*)d_in[1];
  const float* k_w   = (const float*)d_in[2];
  const float* v_w   = (const float*)d_in[3];
  const float* o_w   = (const float*)d_in[4];
  const float* lin_w = (const float*)d_in[5];
  const float* lin_b = (const float*)d_in[6];
  const float* ln_w  = (const float*)d_in[7];
  const float* ln_b  = (const float*)d_in[8];
  const float* W1    = (const float*)d_in[9];
  const float* b1    = (const float*)d_in[10];
  float* out = (float*)d_out;

  const size_t BLC = (size_t)B_ * L_ * C_;
  const size_t CC  = (size_t)C_ * C_;
  _Float16* HF = (_Float16*)d_ws;               // hid f16; later scan output
  _Float16* WF = HF + BLC;
  _Float16* KF = WF + CC;
  _Float16* VF = KF + BLC;
  float*    CO = (float*)(VF + BLC);
  _Float16* QF = (_Float16*)d_out;              // Q f16 in d_out (dead before final GEMM)

  const int M = B_ * L_, N = C_, Kd = C_;
  dim3 gg(N / TN, M / TM);
  const int n8h = (int)(BLC / 8);
  const int n8w = (int)(CC / 8);

  cast_f16<<<(n8h+255)/256, 256, 0, stream>>>(hid, HF, n8h);
  cast_f16<<<(n8w+255)/256, 256, 0, stream>>>(q_w, WF, n8w);
  gemm_f16<_Float16><<<gg, 256, 0, stream>>>(HF, WF, QF, M, N, Kd);
  cast_f16<<<(n8w+255)/256, 256, 0, stream>>>(k_w, WF, n8w);
  gemm_f16<_Float16><<<gg, 256, 0, stream>>>(HF, WF, KF, M, N, Kd);
  cast_f16<<<(n8w+255)/256, 256, 0, stream>>>(v_w, WF, n8w);
  gemm_f16<_Float16><<<gg, 256, 0, stream>>>(HF, WF, VF, M, N, Kd);
  ilr_kernel<<<M / 16, 256, 0, stream>>>(hid, lin_w, lin_b, CO);
  scan_kernel<<<B_ * NH_, 64, 0, stream>>>(QF, KF, VF, CO, W1, b1, ln_w, ln_b, HF);
  cast_f16<<<(n8w+255)/256, 256, 0, stream>>>(o_w, WF, n8w);
  gemm_f16<float><<<gg, 256, 0, stream>>>(HF, WF, out, M, N, Kd);
}

// Round 8
// 1516.934 us; speedup vs baseline: 7.4329x; 1.1667x over previous
//
#include <hip/hip_runtime.h>
#include <hip/hip_bf16.h>

#define B_ 4
#define L_ 4096
#define C_ 2048
#define NH_ 32
#define K_ 16
#define F_ 64
#define NC_ 256
#define EPS_ 1e-6f

typedef _Float16 half8 __attribute__((ext_vector_type(8)));
typedef _Float16 half4 __attribute__((ext_vector_type(4)));
typedef float f32x4 __attribute__((ext_vector_type(4)));

// sum over 16-lane group via DPP (VALU pipe, no LDS): xor1, xor2, ror4, ror8
__device__ __forceinline__ float red16(float v) {
  int x;
  x = __builtin_amdgcn_update_dpp(0, __builtin_bit_cast(int, v), 0xB1, 0xF, 0xF, true); // quad_perm [1,0,3,2] = xor1
  v += __builtin_bit_cast(float, x);
  x = __builtin_amdgcn_update_dpp(0, __builtin_bit_cast(int, v), 0x4E, 0xF, 0xF, true); // quad_perm [2,3,0,1] = xor2
  v += __builtin_bit_cast(float, x);
  x = __builtin_amdgcn_update_dpp(0, __builtin_bit_cast(int, v), 0x124, 0xF, 0xF, true); // row_ror:4
  v += __builtin_bit_cast(float, x);
  x = __builtin_amdgcn_update_dpp(0, __builtin_bit_cast(int, v), 0x128, 0xF, 0xF, true); // row_ror:8
  v += __builtin_bit_cast(float, x);
  return v;
}

__device__ __forceinline__ void gl_lds16(const _Float16* g, _Float16* l) {
  __builtin_amdgcn_global_load_lds(
      (const __attribute__((address_space(1))) void*)g,
      (__attribute__((address_space(3))) void*)l, 16, 0, 0);
}

// ---------------- cast fp32 -> f16, 8 elems/thread ----------------
__global__ __launch_bounds__(256) void cast_f16(const float* __restrict__ in,
                                                _Float16* __restrict__ out, int n8) {
  int i = blockIdx.x * 256 + threadIdx.x;
  if (i >= n8) return;
  const float4* ip = (const float4*)in;
  float4 a = ip[2*i], b = ip[2*i+1];
  half8 o;
  o[0]=(_Float16)a.x; o[1]=(_Float16)a.y; o[2]=(_Float16)a.z; o[3]=(_Float16)a.w;
  o[4]=(_Float16)b.x; o[5]=(_Float16)b.y; o[6]=(_Float16)b.z; o[7]=(_Float16)b.w;
  ((half8*)out)[i] = o;
}

// ---------------- f16 MFMA GEMM (m97 structure) ----------------
#define TM 128
#define TN 128
#define TK 32

template<typename OT>
__global__ __launch_bounds__(256) void gemm_f16(
    const _Float16* __restrict__ A, const _Float16* __restrict__ Bm,
    OT* __restrict__ C, int M, int N, int Kd)
{
  __shared__ __align__(16) _Float16 As[TM*TK];
  __shared__ __align__(16) _Float16 Bs[TN*TK];
  const int t = threadIdx.x;
  const int lane = t & 63;
  const int bn = blockIdx.x, bm = blockIdx.y;
  const int w = t >> 6;
  const int wm = (w >> 1) * 64, wn = (w & 1) * 64;

  const _Float16* ga1 = A  + ((long)(bm*TM +      (t>>2)))*Kd + (t&3)*8;
  const _Float16* ga2 = A  + ((long)(bm*TM + 64 + (t>>2)))*Kd + (t&3)*8;
  const _Float16* gb1 = Bm + ((long)(bn*TN +      (t>>2)))*Kd + (t&3)*8;
  const _Float16* gb2 = Bm + ((long)(bn*TN + 64 + (t>>2)))*Kd + (t&3)*8;
  _Float16* la1 = As + (size_t)t*8;
  _Float16* la2 = As + (size_t)(t+256)*8;
  _Float16* lb1 = Bs + (size_t)t*8;
  _Float16* lb2 = Bs + (size_t)(t+256)*8;

  f32x4 acc[4][4];
#pragma unroll
  for (int i = 0; i < 4; ++i)
#pragma unroll
    for (int j = 0; j < 4; ++j) acc[i][j] = (f32x4){0.f,0.f,0.f,0.f};

  for (int k0 = 0; k0 < Kd; k0 += TK) {
    __syncthreads();
    gl_lds16(ga1 + k0, la1);
    gl_lds16(ga2 + k0, la2);
    gl_lds16(gb1 + k0, lb1);
    gl_lds16(gb2 + k0, lb2);
    __syncthreads();
    half8 af[4], bf[4];
#pragma unroll
    for (int i = 0; i < 4; ++i)
      af[i] = *(const half8*)(As + (size_t)(wm + i*16 + (lane&15))*TK + (lane>>4)*8);
#pragma unroll
    for (int j = 0; j < 4; ++j)
      bf[j] = *(const half8*)(Bs + (size_t)(wn + j*16 + (lane&15))*TK + (lane>>4)*8);
#pragma unroll
    for (int i = 0; i < 4; ++i)
#pragma unroll
      for (int j = 0; j < 4; ++j)
        acc[i][j] = __builtin_amdgcn_mfma_f32_16x16x32_f16(af[i], bf[j], acc[i][j], 0, 0, 0);
  }

  const int cr = (lane >> 4) * 4, cc = lane & 15;
#pragma unroll
  for (int i = 0; i < 4; ++i)
#pragma unroll
    for (int j = 0; j < 4; ++j)
#pragma unroll
      for (int r = 0; r < 4; ++r) {
        long row = (long)bm*TM + wm + i*16 + cr + r;
        long col = (long)bn*TN + wn + j*16 + cc;
        C[row*(long)N + col] = (OT)acc[i][j][r];
      }
}

// ---------------- ilr / coeff (fp32) ----------------
__global__ __launch_bounds__(256) void ilr_kernel(
    const float* __restrict__ hid, const float* __restrict__ lin_w,
    const float* __restrict__ lin_b, float* __restrict__ coeff)
{
  const int t = threadIdx.x;
  const int lane = t & 63;
  const int w = t >> 6;
  const int row0 = blockIdx.x * 16 + w * 4;

  float4 hv[4][8];
#pragma unroll
  for (int r = 0; r < 4; ++r) {
    const float* hp = hid + (size_t)(row0 + r) * C_;
#pragma unroll
    for (int i = 0; i < 8; ++i) hv[r][i] = *(const float4*)(hp + i*256 + lane*4);
  }
  float res[4] = {0.f,0.f,0.f,0.f};
  for (int h = 0; h < NH_; ++h) {
    const float* wp = lin_w + (size_t)h * C_;
    float s[4] = {0.f,0.f,0.f,0.f};
#pragma unroll
    for (int i = 0; i < 8; ++i) {
      float4 wv = *(const float4*)(wp + i*256 + lane*4);
#pragma unroll
      for (int r = 0; r < 4; ++r)
        s[r] += hv[r][i].x*wv.x + hv[r][i].y*wv.y + hv[r][i].z*wv.z + hv[r][i].w*wv.w;
    }
#pragma unroll
    for (int o = 32; o > 0; o >>= 1)
#pragma unroll
      for (int r = 0; r < 4; ++r) s[r] += __shfl_xor(s[r], o, 64);
    if (lane == h) { res[0]=s[0]; res[1]=s[1]; res[2]=s[2]; res[3]=s[3]; }
  }
  if (lane < NH_) {
    float lb = lin_b[lane];
#pragma unroll
    for (int r = 0; r < 4; ++r) {
      int row = row0 + r;
      int b = row >> 12;
      int li = row & (L_ - 1);
      int k = li & (K_ - 1);
      float x = res[r] + lb;
      float sp = (x > 20.f) ? x : log1pf(expf(x));
      float v = (1.0f / (float)(k + 1)) * sp * (1.0f / (float)F_);
      coeff[((size_t)(b * NH_ + lane)) * L_ + li] = v;
    }
  }
}

// ---------------- TTT scan v5: v4 + DPP reductions ----------
// Layouts (16x16x16 MFMA, q=lane>>4, ln=lane&15):
//   A-frag: lane holds A[ln][4q+j];  B-frag: B[4q+j][ln];  C/D: C[4q+r][ln].
// Identity-transpose: (M@I) relays A-frag of M into C/D positions.
// W1 = Whi (f16, persistent) + Wlo (f32 residual, absorbs all updates).

struct Ck {
  half4 xbA[4], xcA[4], xaA[4];  // A-frags per feature-tile
  float co4[4], co15;
};

__device__ __forceinline__ void load_ck(
    Ck& c, const _Float16* Q, const _Float16* Kp, const _Float16* V,
    const float* co, size_t rowbase, int hoff, size_t cobase, int n, int q, int ln)
{
#pragma unroll
  for (int kt = 0; kt < 4; ++kt) {
    size_t idx = (rowbase + ln) * C_ + hoff + 16*kt + 4*q;
    c.xbA[kt] = *(const half4*)(Kp + idx);
    c.xcA[kt] = *(const half4*)(Q  + idx);
    c.xaA[kt] = *(const half4*)(V  + idx);
  }
#pragma unroll
  for (int r = 0; r < 4; ++r) c.co4[r] = co[cobase + (size_t)n*K_ + 4*q + r];
  c.co15 = co[cobase + (size_t)n*K_ + 15];
}

__global__ __launch_bounds__(64, 1) void scan_kernel(
    const _Float16* __restrict__ Q, const _Float16* __restrict__ Kp,
    const _Float16* __restrict__ V,
    const float* __restrict__ coeff, const float* __restrict__ W1g, const float* __restrict__ b1g,
    const float* __restrict__ ln_w, const float* __restrict__ ln_b,
    _Float16* __restrict__ OF)
{
  const int bh = blockIdx.x;
  const int b = bh >> 5, h = bh & 31;
  const int lane = threadIdx.x;
  const int q = lane >> 4, ln = lane & 15;
  const int hoff = h * F_;
  const size_t cobase = (size_t)bh * L_;
  const size_t brow = (size_t)b * L_;

  // persistent W1 state: f16 hi (never re-split) + f32 lo residual
  half4 Whi[4][4];
  f32x4 Wlo[4][4];
#pragma unroll
  for (int kt = 0; kt < 4; ++kt)
#pragma unroll
    for (int t = 0; t < 4; ++t) {
      half4 hv; f32x4 lv;
#pragma unroll
      for (int j = 0; j < 4; ++j) {
        float wv = W1g[(size_t)h*F_*F_ + (size_t)(16*kt + 4*q + j)*F_ + 16*t + ln];
        _Float16 hi = (_Float16)wv;
        hv[j] = hi; lv[j] = wv - (float)hi;
      }
      Whi[kt][t] = hv; Wlo[kt][t] = lv;
    }
  float b1r[4], gamt[4], bett[4];
#pragma unroll
  for (int t = 0; t < 4; ++t) {
    b1r[t]  = b1g[hoff + 16*t + ln];
    gamt[t] = ln_w[hoff + 16*t + ln];
    bett[t] = ln_b[hoff + 16*t + ln];
  }
  half4 maskA, maskI;
#pragma unroll
  for (int j = 0; j < 4; ++j) {
    maskA[j] = (_Float16)((4*q + j <= ln) ? 1.f : 0.f);
    maskI[j] = (_Float16)((4*q + j == ln) ? 1.f : 0.f);
  }
  const f32x4 zf4 = (f32x4){0.f, 0.f, 0.f, 0.f};

  auto body = [&](const Ck& ck, int n) {
    const size_t rowbase = brow + (size_t)n * K_;

    // 0. f16 view of the lo residual
    half4 Wlo16[4][4];
#pragma unroll
    for (int kt = 0; kt < 4; ++kt)
#pragma unroll
      for (int t = 0; t < 4; ++t) {
        half4 lv;
#pragma unroll
        for (int j = 0; j < 4; ++j) lv[j] = (_Float16)Wlo[kt][t][j];
        Wlo16[kt][t] = lv;
      }

    // 0b. identity-transposes: tg=(xa-xb), xcs, xbT into C/D positions
    f32x4 tgD[4], xcsD[4];
    half4 xbT[4];
#pragma unroll
    for (int t = 0; t < 4; ++t) {
      half4 dd = ck.xaA[t] - ck.xbA[t];
      tgD[t]  = __builtin_amdgcn_mfma_f32_16x16x16f16(dd, maskI, zf4, 0, 0, 0);
      xcsD[t] = __builtin_amdgcn_mfma_f32_16x16x16f16(ck.xcA[t], maskI, zf4, 0, 0, 0);
      f32x4 x = __builtin_amdgcn_mfma_f32_16x16x16f16(ck.xbA[t], maskI, zf4, 0, 0, 0);
      half4 v;
#pragma unroll
      for (int r = 0; r < 4; ++r) v[r] = (_Float16)x[r];
      xbT[t] = v;
    }

    // 1. z = xb@W1 + b1 (hi/lo chains split for ILP)
    f32x4 za[4];
#pragma unroll
    for (int t = 0; t < 4; ++t) {
      f32x4 zh = (f32x4){b1r[t], b1r[t], b1r[t], b1r[t]};
      f32x4 zl = zf4;
#pragma unroll
      for (int kt = 0; kt < 4; ++kt) {
        zh = __builtin_amdgcn_mfma_f32_16x16x16f16(ck.xbA[kt], Whi[kt][t],   zh, 0, 0, 0);
        zl = __builtin_amdgcn_mfma_f32_16x16x16f16(ck.xbA[kt], Wlo16[kt][t], zl, 0, 0, 0);
      }
      za[t] = zh + zl;
    }

    // 2. attnT = xb@xc^T (2+2 split), masked -> f16 A-frag of attn
    f32x4 at0 = zf4, at1 = zf4;
    at0 = __builtin_amdgcn_mfma_f32_16x16x16f16(ck.xbA[0], ck.xcA[0], at0, 0, 0, 0);
    at0 = __builtin_amdgcn_mfma_f32_16x16x16f16(ck.xbA[1], ck.xcA[1], at0, 0, 0, 0);
    at1 = __builtin_amdgcn_mfma_f32_16x16x16f16(ck.xbA[2], ck.xcA[2], at1, 0, 0, 0);
    at1 = __builtin_amdgcn_mfma_f32_16x16x16f16(ck.xbA[3], ck.xcA[3], at1, 0, 0, 0);
    f32x4 at = at0 + at1;
    half4 atf;
#pragma unroll
    for (int r = 0; r < 4; ++r) atf[r] = (_Float16)((4*q + r <= ln) ? at[r] : 0.f);

    // 3. LN-L2 backward -> gZ (single-pass mean/var; DPP reductions)
    half4 gzf[4];
#pragma unroll
    for (int r = 0; r < 4; ++r) {
      float zr[4], s1 = 0.f, s2 = 0.f;
#pragma unroll
      for (int t = 0; t < 4; ++t) { zr[t] = za[t][r]; s1 += zr[t]; s2 += zr[t]*zr[t]; }
      s1 = red16(s1); s2 = red16(s2);
      float mu = s1 * (1.f/F_);
      float istd = rsqrtf(s2 * (1.f/F_) - mu*mu + EPS_);
      float xh[4], gy[4], sg = 0.f, sx = 0.f;
#pragma unroll
      for (int t = 0; t < 4; ++t) {
        xh[t] = (zr[t] - mu) * istd;
        gy[t] = (gamt[t]*xh[t] + bett[t] - tgD[t][r]) * gamt[t];
        sg += gy[t]; sx += gy[t]*xh[t];
      }
      sg = red16(sg); sx = red16(sx);
      const float sc = istd * (1.f/F_);
#pragma unroll
      for (int t = 0; t < 4; ++t)
        gzf[t][r] = (_Float16)((F_*gy[t] - sg - xh[t]*sx) * sc);
    }

    // 4. cum = maskL@gZ ; ag = attn@gZ
    f32x4 cum[4], ag[4];
#pragma unroll
    for (int t = 0; t < 4; ++t) {
      cum[t] = __builtin_amdgcn_mfma_f32_16x16x16f16(maskA, gzf[t], zf4, 0, 0, 0);
      ag[t]  = __builtin_amdgcn_mfma_f32_16x16x16f16(atf,   gzf[t], zf4, 0, 0, 0);
    }

    // 5. zb = xc@W1 + b1 - co*(ag + cum)
    float zbf[4][4];
#pragma unroll
    for (int t = 0; t < 4; ++t) {
      f32x4 zh = zf4, zl = zf4;
#pragma unroll
      for (int kt = 0; kt < 4; ++kt) {
        zh = __builtin_amdgcn_mfma_f32_16x16x16f16(ck.xcA[kt], Whi[kt][t],   zh, 0, 0, 0);
        zl = __builtin_amdgcn_mfma_f32_16x16x16f16(ck.xcA[kt], Wlo16[kt][t], zl, 0, 0, 0);
      }
      f32x4 s = zh + zl;
#pragma unroll
      for (int r = 0; r < 4; ++r)
        zbf[t][r] = s[r] + b1r[t] - ck.co4[r]*(ag[t][r] + cum[t][r]);
    }

    // 6. out = xc + LN(zb) (single-pass mean/var, DPP), scalar f16 stores
#pragma unroll
    for (int r = 0; r < 4; ++r) {
      float zr[4], s1 = 0.f, s2 = 0.f;
#pragma unroll
      for (int t = 0; t < 4; ++t) { zr[t] = zbf[t][r]; s1 += zr[t]; s2 += zr[t]*zr[t]; }
      s1 = red16(s1); s2 = red16(s2);
      float mu = s1 * (1.f/F_);
      float istd = rsqrtf(s2 * (1.f/F_) - mu*mu + EPS_);
#pragma unroll
      for (int t = 0; t < 4; ++t) {
        float ov = xcsD[t][r] + gamt[t]*((zr[t] - mu)*istd) + bett[t];
        OF[(rowbase + 4*q + r) * C_ + hoff + 16*t + ln] = (_Float16)ov;
      }
    }

    // 7. b1 <- row 15 of b1_bar (lanes q==3, reg r=3)
#pragma unroll
    for (int t = 0; t < 4; ++t) {
      float tmp = b1r[t] - ck.co15 * cum[t][3];
      b1r[t] = __shfl(tmp, 48 + ln, 64);
    }

    // 8. W1 residual update: Wlo -= co15 * xb^T@gZ
#pragma unroll
    for (int mt = 0; mt < 4; ++mt)
#pragma unroll
      for (int t = 0; t < 4; ++t) {
        f32x4 d = __builtin_amdgcn_mfma_f32_16x16x16f16(xbT[mt], gzf[t], zf4, 0, 0, 0);
#pragma unroll
        for (int r = 0; r < 4; ++r) Wlo[mt][t][r] -= ck.co15 * d[r];
      }
  };

  Ck cka, ckb;
  load_ck(cka, Q, Kp, V, coeff, brow, hoff, cobase, 0, q, ln);
  for (int n = 0; n < NC_; n += 2) {
    load_ck(ckb, Q, Kp, V, coeff, brow + (size_t)(n+1)*K_, hoff, cobase, n+1, q, ln);
    body(cka, n);
    int np = (n + 2 < NC_) ? n + 2 : NC_ - 1;
    load_ck(cka, Q, Kp, V, coeff, brow + (size_t)np*K_, hoff, cobase, np, q, ln);
    body(ckb, n + 1);
  }
}

extern "C" void kernel_launch(void* const* d_in, const int* in_sizes, int n_in,
                              void* d_out, int out_size, void* d_ws, size_t ws_size,
                              hipStream_t stream)
{
  const float* hid   = (const float*)d_in[0];
  const float* q_w   = (const float*)d_in[1];
  const float* k_w   = (const float*)d_in[2];
  const float* v_w   = (const float*)d_in[3];
  const float* o_w   = (const float*)d_in[4];
  const float* lin_w = (const float*)d_in[5];
  const float* lin_b = (const float*)d_in[6];
  const float* ln_w  = (const float*)d_in[7];
  const float* ln_b  = (const float*)d_in[8];
  const float* W1    = (const float*)d_in[9];
  const float* b1    = (const float*)d_in[10];
  float* out = (float*)d_out;

  const size_t BLC = (size_t)B_ * L_ * C_;
  const size_t CC  = (size_t)C_ * C_;
  _Float16* HF = (_Float16*)d_ws;               // hid f16; later scan output
  _Float16* WF = HF + BLC;
  _Float16* KF = WF + CC;
  _Float16* VF = KF + BLC;
  float*    CO = (float*)(VF + BLC);
  _Float16* QF = (_Float16*)d_out;              // Q f16 in d_out (dead before final GEMM)

  const int M = B_ * L_, N = C_, Kd = C_;
  dim3 gg(N / TN, M / TM);
  const int n8h = (int)(BLC / 8);
  const int n8w = (int)(CC / 8);

  cast_f16<<<(n8h+255)/256, 256, 0, stream>>>(hid, HF, n8h);
  cast_f16<<<(n8w+255)/256, 256, 0, stream>>>(q_w, WF, n8w);
  gemm_f16<_Float16><<<gg, 256, 0, stream>>>(HF, WF, QF, M, N, Kd);
  cast_f16<<<(n8w+255)/256, 256, 0, stream>>>(k_w, WF, n8w);
  gemm_f16<_Float16><<<gg, 256, 0, stream>>>(HF, WF, KF, M, N, Kd);
  cast_f16<<<(n8w+255)/256, 256, 0, stream>>>(v_w, WF, n8w);
  gemm_f16<_Float16><<<gg, 256, 0, stream>>>(HF, WF, VF, M, N, Kd);
  ilr_kernel<<<M / 16, 256, 0, stream>>>(hid, lin_w, lin_b, CO);
  scan_kernel<<<B_ * NH_, 64, 0, stream>>>(QF, KF, VF, CO, W1, b1, ln_w, ln_b, HF);
  cast_f16<<<(n8w+255)/256, 256, 0, stream>>>(o_w, WF, n8w);
  gemm_f16<float><<<gg, 256, 0, stream>>>(HF, WF, out, M, N, Kd);
}

// Round 9
// 1433.182 us; speedup vs baseline: 7.8673x; 1.0584x over previous
//
#include <hip/hip_runtime.h>
#include <hip/hip_bf16.h>

#define B_ 4
#define L_ 4096
#define C_ 2048
#define NH_ 32
#define K_ 16
#define F_ 64
#define NC_ 256
#define EPS_ 1e-6f

typedef _Float16 half8 __attribute__((ext_vector_type(8)));
typedef _Float16 half4 __attribute__((ext_vector_type(4)));
typedef float f32x4 __attribute__((ext_vector_type(4)));

// sum over 16-lane group via DPP (VALU pipe, no LDS): xor1, xor2, ror4, ror8
__device__ __forceinline__ float red16(float v) {
  int x;
  x = __builtin_amdgcn_update_dpp(0, __builtin_bit_cast(int, v), 0xB1, 0xF, 0xF, true);
  v += __builtin_bit_cast(float, x);
  x = __builtin_amdgcn_update_dpp(0, __builtin_bit_cast(int, v), 0x4E, 0xF, 0xF, true);
  v += __builtin_bit_cast(float, x);
  x = __builtin_amdgcn_update_dpp(0, __builtin_bit_cast(int, v), 0x124, 0xF, 0xF, true);
  v += __builtin_bit_cast(float, x);
  x = __builtin_amdgcn_update_dpp(0, __builtin_bit_cast(int, v), 0x128, 0xF, 0xF, true);
  v += __builtin_bit_cast(float, x);
  return v;
}

__device__ __forceinline__ void gl_lds16(const _Float16* g, _Float16* l) {
  __builtin_amdgcn_global_load_lds(
      (const __attribute__((address_space(1))) void*)g,
      (__attribute__((address_space(3))) void*)l, 16, 0, 0);
}

// ---------------- cast fp32 -> f16, 8 elems/thread ----------------
__global__ __launch_bounds__(256) void cast_f16(const float* __restrict__ in,
                                                _Float16* __restrict__ out, int n8) {
  int i = blockIdx.x * 256 + threadIdx.x;
  if (i >= n8) return;
  const float4* ip = (const float4*)in;
  float4 a = ip[2*i], b = ip[2*i+1];
  half8 o;
  o[0]=(_Float16)a.x; o[1]=(_Float16)a.y; o[2]=(_Float16)a.z; o[3]=(_Float16)a.w;
  o[4]=(_Float16)b.x; o[5]=(_Float16)b.y; o[6]=(_Float16)b.z; o[7]=(_Float16)b.w;
  ((half8*)out)[i] = o;
}

// ---------------- f16 MFMA GEMM (m97 structure) ----------------
#define TM 128
#define TN 128
#define TK 32

template<typename OT>
__global__ __launch_bounds__(256) void gemm_f16(
    const _Float16* __restrict__ A, const _Float16* __restrict__ Bm,
    OT* __restrict__ C, int M, int N, int Kd)
{
  __shared__ __align__(16) _Float16 As[TM*TK];
  __shared__ __align__(16) _Float16 Bs[TN*TK];
  const int t = threadIdx.x;
  const int lane = t & 63;
  const int bn = blockIdx.x, bm = blockIdx.y;
  const int w = t >> 6;
  const int wm = (w >> 1) * 64, wn = (w & 1) * 64;

  const _Float16* ga1 = A  + ((long)(bm*TM +      (t>>2)))*Kd + (t&3)*8;
  const _Float16* ga2 = A  + ((long)(bm*TM + 64 + (t>>2)))*Kd + (t&3)*8;
  const _Float16* gb1 = Bm + ((long)(bn*TN +      (t>>2)))*Kd + (t&3)*8;
  const _Float16* gb2 = Bm + ((long)(bn*TN + 64 + (t>>2)))*Kd + (t&3)*8;
  _Float16* la1 = As + (size_t)t*8;
  _Float16* la2 = As + (size_t)(t+256)*8;
  _Float16* lb1 = Bs + (size_t)t*8;
  _Float16* lb2 = Bs + (size_t)(t+256)*8;

  f32x4 acc[4][4];
#pragma unroll
  for (int i = 0; i < 4; ++i)
#pragma unroll
    for (int j = 0; j < 4; ++j) acc[i][j] = (f32x4){0.f,0.f,0.f,0.f};

  for (int k0 = 0; k0 < Kd; k0 += TK) {
    __syncthreads();
    gl_lds16(ga1 + k0, la1);
    gl_lds16(ga2 + k0, la2);
    gl_lds16(gb1 + k0, lb1);
    gl_lds16(gb2 + k0, lb2);
    __syncthreads();
    half8 af[4], bf[4];
#pragma unroll
    for (int i = 0; i < 4; ++i)
      af[i] = *(const half8*)(As + (size_t)(wm + i*16 + (lane&15))*TK + (lane>>4)*8);
#pragma unroll
    for (int j = 0; j < 4; ++j)
      bf[j] = *(const half8*)(Bs + (size_t)(wn + j*16 + (lane&15))*TK + (lane>>4)*8);
#pragma unroll
    for (int i = 0; i < 4; ++i)
#pragma unroll
      for (int j = 0; j < 4; ++j)
        acc[i][j] = __builtin_amdgcn_mfma_f32_16x16x32_f16(af[i], bf[j], acc[i][j], 0, 0, 0);
  }

  const int cr = (lane >> 4) * 4, cc = lane & 15;
#pragma unroll
  for (int i = 0; i < 4; ++i)
#pragma unroll
    for (int j = 0; j < 4; ++j)
#pragma unroll
      for (int r = 0; r < 4; ++r) {
        long row = (long)bm*TM + wm + i*16 + cr + r;
        long col = (long)bn*TN + wn + j*16 + cc;
        C[row*(long)N + col] = (OT)acc[i][j][r];
      }
}

// ---------------- ilr / coeff (fp32) ----------------
__global__ __launch_bounds__(256) void ilr_kernel(
    const float* __restrict__ hid, const float* __restrict__ lin_w,
    const float* __restrict__ lin_b, float* __restrict__ coeff)
{
  const int t = threadIdx.x;
  const int lane = t & 63;
  const int w = t >> 6;
  const int row0 = blockIdx.x * 16 + w * 4;

  float4 hv[4][8];
#pragma unroll
  for (int r = 0; r < 4; ++r) {
    const float* hp = hid + (size_t)(row0 + r) * C_;
#pragma unroll
    for (int i = 0; i < 8; ++i) hv[r][i] = *(const float4*)(hp + i*256 + lane*4);
  }
  float res[4] = {0.f,0.f,0.f,0.f};
  for (int h = 0; h < NH_; ++h) {
    const float* wp = lin_w + (size_t)h * C_;
    float s[4] = {0.f,0.f,0.f,0.f};
#pragma unroll
    for (int i = 0; i < 8; ++i) {
      float4 wv = *(const float4*)(wp + i*256 + lane*4);
#pragma unroll
      for (int r = 0; r < 4; ++r)
        s[r] += hv[r][i].x*wv.x + hv[r][i].y*wv.y + hv[r][i].z*wv.z + hv[r][i].w*wv.w;
    }
#pragma unroll
    for (int o = 32; o > 0; o >>= 1)
#pragma unroll
      for (int r = 0; r < 4; ++r) s[r] += __shfl_xor(s[r], o, 64);
    if (lane == h) { res[0]=s[0]; res[1]=s[1]; res[2]=s[2]; res[3]=s[3]; }
  }
  if (lane < NH_) {
    float lb = lin_b[lane];
#pragma unroll
    for (int r = 0; r < 4; ++r) {
      int row = row0 + r;
      int b = row >> 12;
      int li = row & (L_ - 1);
      int k = li & (K_ - 1);
      float x = res[r] + lb;
      float sp = (x > 20.f) ? x : log1pf(expf(x));
      float v = (1.0f / (float)(k + 1)) * sp * (1.0f / (float)F_);
      coeff[((size_t)(b * NH_ + lane)) * L_ + li] = v;
    }
  }
}

// ---------------- TTT scan v6: 2-wave pipeline per (b,h) ----------------
// wave0 (producer): za = xb@W1+b1 -> LN-L2 -> gZ, publishes gZ via LDS.
// wave1 (consumer): one chunk behind: attnT, cum/ag, zb, LN, out-store.
// BOTH waves maintain bit-identical W1 (Whi f16 + Wlo f32) and b1 replicas:
// each applies the same deterministic MFMA delta from the same f16 gZ.
// gZ handoff: 4-slot rotating LDS buffer, ONE __syncthreads per chunk.
// (Reader's slot j&3 is only rewritten by the producer at chunk j+4, which
//  is >= 2 barriers after the read -> race-free with >=3 slots.)
// Layouts (16x16x16 MFMA, q=lane>>4, ln=lane&15):
//   A-frag: A[ln][4q+j];  B-frag: B[4q+j][ln];  C/D: C[4q+r][ln] (== B-frag).
// Identity-transpose: (M@I) relays A-frag of M into C/D positions.

struct Ck2 {
  half4 xbA[4], xsA[4];   // xb + second tensor (V for wave0, Q for wave1)
  float co4[4], co15;
};

__device__ __forceinline__ void load_ck2(
    Ck2& c, const _Float16* Kp, const _Float16* S, const float* co,
    size_t rowbase, int hoff, size_t cobase, int n, int q, int ln)
{
#pragma unroll
  for (int kt = 0; kt < 4; ++kt) {
    size_t idx = (rowbase + ln) * C_ + hoff + 16*kt + 4*q;
    c.xbA[kt] = *(const half4*)(Kp + idx);
    c.xsA[kt] = *(const half4*)(S  + idx);
  }
#pragma unroll
  for (int r = 0; r < 4; ++r) c.co4[r] = co[cobase + (size_t)n*K_ + 4*q + r];
  c.co15 = co[cobase + (size_t)n*K_ + 15];
}

__global__ __launch_bounds__(128, 1) void scan_kernel(
    const _Float16* __restrict__ Q, const _Float16* __restrict__ Kp,
    const _Float16* __restrict__ V,
    const float* __restrict__ coeff, const float* __restrict__ W1g, const float* __restrict__ b1g,
    const float* __restrict__ ln_w, const float* __restrict__ ln_b,
    _Float16* __restrict__ OF)
{
  const int bh = blockIdx.x;
  const int b = bh >> 5, h = bh & 31;
  const int tid = threadIdx.x;
  const int lane = tid & 63;
  const bool isP = tid < 64;                 // producer wave
  const int q = lane >> 4, ln = lane & 15;
  const int hoff = h * F_;
  const size_t cobase = (size_t)bh * L_;
  const size_t brow = (size_t)b * L_;

  __shared__ half4 gzs[4][4][64];            // [slot][t][lane], 8 KB

  // ---- replica state (both waves) ----
  half4 Whi[4][4];
  f32x4 Wlo[4][4];
#pragma unroll
  for (int kt = 0; kt < 4; ++kt)
#pragma unroll
    for (int t = 0; t < 4; ++t) {
      half4 hv; f32x4 lv;
#pragma unroll
      for (int j = 0; j < 4; ++j) {
        float wv = W1g[(size_t)h*F_*F_ + (size_t)(16*kt + 4*q + j)*F_ + 16*t + ln];
        _Float16 hi = (_Float16)wv;
        hv[j] = hi; lv[j] = wv - (float)hi;
      }
      Whi[kt][t] = hv; Wlo[kt][t] = lv;
    }
  float b1r[4], gamt[4], bett[4];
#pragma unroll
  for (int t = 0; t < 4; ++t) {
    b1r[t]  = b1g[hoff + 16*t + ln];
    gamt[t] = ln_w[hoff + 16*t + ln];
    bett[t] = ln_b[hoff + 16*t + ln];
  }
  half4 maskA, maskI;
#pragma unroll
  for (int j = 0; j < 4; ++j) {
    maskA[j] = (_Float16)((4*q + j <= ln) ? 1.f : 0.f);
    maskI[j] = (_Float16)((4*q + j == ln) ? 1.f : 0.f);
  }
  const f32x4 zf4 = (f32x4){0.f, 0.f, 0.f, 0.f};

  const _Float16* S = isP ? V : Q;

  // one pipeline iteration: producer handles chunk i (cur), prefetches i+1
  // into nxt; consumer prefetches chunk i into nxt, consumes chunk i-1 (cur).
  auto iter = [&](int i, Ck2& cur, Ck2& nxt) {
    half4 gzf[4];     // producer keeps own gZ across the barrier
    half4 xbTp[4];    // producer's xb^T A-frags
    float co15p = 0.f;

    if (isP) {
      if (i < NC_) {
        co15p = cur.co15;
        if (i + 1 < NC_)
          load_ck2(nxt, Kp, S, coeff, brow + (size_t)(i+1)*K_, hoff, cobase, i+1, q, ln);
        // Wlo16 view
        half4 Wlo16[4][4];
#pragma unroll
        for (int kt = 0; kt < 4; ++kt)
#pragma unroll
          for (int t = 0; t < 4; ++t) {
            half4 lv;
#pragma unroll
            for (int j = 0; j < 4; ++j) lv[j] = (_Float16)Wlo[kt][t][j];
            Wlo16[kt][t] = lv;
          }
        // transposes: tg = (xa - xb) into C/D; xb^T A-frag
        f32x4 tgD[4];
#pragma unroll
        for (int t = 0; t < 4; ++t) {
          half4 dd = cur.xsA[t] - cur.xbA[t];
          tgD[t] = __builtin_amdgcn_mfma_f32_16x16x16f16(dd, maskI, zf4, 0, 0, 0);
          f32x4 x = __builtin_amdgcn_mfma_f32_16x16x16f16(cur.xbA[t], maskI, zf4, 0, 0, 0);
          half4 v;
#pragma unroll
          for (int r = 0; r < 4; ++r) v[r] = (_Float16)x[r];
          xbTp[t] = v;
        }
        // za = xb@W1 + b1 (hi/lo split)
        f32x4 za[4];
#pragma unroll
        for (int t = 0; t < 4; ++t) {
          f32x4 zh = (f32x4){b1r[t], b1r[t], b1r[t], b1r[t]};
          f32x4 zl = zf4;
#pragma unroll
          for (int kt = 0; kt < 4; ++kt) {
            zh = __builtin_amdgcn_mfma_f32_16x16x16f16(cur.xbA[kt], Whi[kt][t],   zh, 0, 0, 0);
            zl = __builtin_amdgcn_mfma_f32_16x16x16f16(cur.xbA[kt], Wlo16[kt][t], zl, 0, 0, 0);
          }
          za[t] = zh + zl;
        }
        // LN-L2 backward -> gZ
#pragma unroll
        for (int r = 0; r < 4; ++r) {
          float zr[4], s1 = 0.f, s2 = 0.f;
#pragma unroll
          for (int t = 0; t < 4; ++t) { zr[t] = za[t][r]; s1 += zr[t]; s2 += zr[t]*zr[t]; }
          s1 = red16(s1); s2 = red16(s2);
          float mu = s1 * (1.f/F_);
          float istd = rsqrtf(s2 * (1.f/F_) - mu*mu + EPS_);
          float xh[4], gy[4], sg = 0.f, sx = 0.f;
#pragma unroll
          for (int t = 0; t < 4; ++t) {
            xh[t] = (zr[t] - mu) * istd;
            gy[t] = (gamt[t]*xh[t] + bett[t] - tgD[t][r]) * gamt[t];
            sg += gy[t]; sx += gy[t]*xh[t];
          }
          sg = red16(sg); sx = red16(sx);
          const float sc = istd * (1.f/F_);
#pragma unroll
          for (int t = 0; t < 4; ++t)
            gzf[t][r] = (_Float16)((F_*gy[t] - sg - xh[t]*sx) * sc);
        }
        // publish gZ
#pragma unroll
        for (int t = 0; t < 4; ++t) gzs[i & 3][t][lane] = gzf[t];
      }
    } else {
      if (i < NC_)
        load_ck2(nxt, Kp, S, coeff, brow + (size_t)i*K_, hoff, cobase, i, q, ln);
    }

    __syncthreads();

    if (isP) {
      if (i < NC_) {
        // cum for b1 update; delta; replica update
        f32x4 cum3[4];
#pragma unroll
        for (int t = 0; t < 4; ++t)
          cum3[t] = __builtin_amdgcn_mfma_f32_16x16x16f16(maskA, gzf[t], zf4, 0, 0, 0);
#pragma unroll
        for (int t = 0; t < 4; ++t) {
          float tmp = b1r[t] - co15p * cum3[t][3];
          b1r[t] = __shfl(tmp, 48 + ln, 64);
        }
#pragma unroll
        for (int mt = 0; mt < 4; ++mt)
#pragma unroll
          for (int t = 0; t < 4; ++t) {
            f32x4 d = __builtin_amdgcn_mfma_f32_16x16x16f16(xbTp[mt], gzf[t], zf4, 0, 0, 0);
#pragma unroll
            for (int r = 0; r < 4; ++r) Wlo[mt][t][r] -= co15p * d[r];
          }
      }
    } else {
      if (i > 0) {
        const int jc = i - 1;
        const size_t rowbase = brow + (size_t)jc * K_;
        // receive gZ
        half4 gz[4];
#pragma unroll
        for (int t = 0; t < 4; ++t) gz[t] = gzs[jc & 3][t][lane];
        // transposes: xc into C/D (for output), xb^T A-frag (for delta)
        f32x4 xcsD[4]; half4 xbT[4];
#pragma unroll
        for (int t = 0; t < 4; ++t) {
          xcsD[t] = __builtin_amdgcn_mfma_f32_16x16x16f16(cur.xsA[t], maskI, zf4, 0, 0, 0);
          f32x4 x = __builtin_amdgcn_mfma_f32_16x16x16f16(cur.xbA[t], maskI, zf4, 0, 0, 0);
          half4 v;
#pragma unroll
          for (int r = 0; r < 4; ++r) v[r] = (_Float16)x[r];
          xbT[t] = v;
        }
        // attnT = xb@xc^T, masked -> A-frag of attn
        f32x4 at0 = zf4, at1 = zf4;
        at0 = __builtin_amdgcn_mfma_f32_16x16x16f16(cur.xbA[0], cur.xsA[0], at0, 0, 0, 0);
        at0 = __builtin_amdgcn_mfma_f32_16x16x16f16(cur.xbA[1], cur.xsA[1], at0, 0, 0, 0);
        at1 = __builtin_amdgcn_mfma_f32_16x16x16f16(cur.xbA[2], cur.xsA[2], at1, 0, 0, 0);
        at1 = __builtin_amdgcn_mfma_f32_16x16x16f16(cur.xbA[3], cur.xsA[3], at1, 0, 0, 0);
        f32x4 at = at0 + at1;
        half4 atf;
#pragma unroll
        for (int r = 0; r < 4; ++r) atf[r] = (_Float16)((4*q + r <= ln) ? at[r] : 0.f);
        // cum / ag
        f32x4 cum[4], ag[4];
#pragma unroll
        for (int t = 0; t < 4; ++t) {
          cum[t] = __builtin_amdgcn_mfma_f32_16x16x16f16(maskA, gz[t], zf4, 0, 0, 0);
          ag[t]  = __builtin_amdgcn_mfma_f32_16x16x16f16(atf,   gz[t], zf4, 0, 0, 0);
        }
        // Wlo16 view
        half4 Wlo16[4][4];
#pragma unroll
        for (int kt = 0; kt < 4; ++kt)
#pragma unroll
          for (int t = 0; t < 4; ++t) {
            half4 lv;
#pragma unroll
            for (int j = 0; j < 4; ++j) lv[j] = (_Float16)Wlo[kt][t][j];
            Wlo16[kt][t] = lv;
          }
        // zb = xc@W1 + b1 - co*(ag+cum)
        float zbf[4][4];
#pragma unroll
        for (int t = 0; t < 4; ++t) {
          f32x4 zh = zf4, zl = zf4;
#pragma unroll
          for (int kt = 0; kt < 4; ++kt) {
            zh = __builtin_amdgcn_mfma_f32_16x16x16f16(cur.xsA[kt], Whi[kt][t],   zh, 0, 0, 0);
            zl = __builtin_amdgcn_mfma_f32_16x16x16f16(cur.xsA[kt], Wlo16[kt][t], zl, 0, 0, 0);
          }
          f32x4 s = zh + zl;
#pragma unroll
          for (int r = 0; r < 4; ++r)
            zbf[t][r] = s[r] + b1r[t] - cur.co4[r]*(ag[t][r] + cum[t][r]);
        }
        // out = xc + LN(zb)
#pragma unroll
        for (int r = 0; r < 4; ++r) {
          float zr[4], s1 = 0.f, s2 = 0.f;
#pragma unroll
          for (int t = 0; t < 4; ++t) { zr[t] = zbf[t][r]; s1 += zr[t]; s2 += zr[t]*zr[t]; }
          s1 = red16(s1); s2 = red16(s2);
          float mu = s1 * (1.f/F_);
          float istd = rsqrtf(s2 * (1.f/F_) - mu*mu + EPS_);
#pragma unroll
          for (int t = 0; t < 4; ++t) {
            float ov = xcsD[t][r] + gamt[t]*((zr[t] - mu)*istd) + bett[t];
            OF[(rowbase + 4*q + r) * C_ + hoff + 16*t + ln] = (_Float16)ov;
          }
        }
        // replica updates (b1, W1) for chunk jc
#pragma unroll
        for (int t = 0; t < 4; ++t) {
          float tmp = b1r[t] - cur.co15 * cum[t][3];
          b1r[t] = __shfl(tmp, 48 + ln, 64);
        }
#pragma unroll
        for (int mt = 0; mt < 4; ++mt)
#pragma unroll
          for (int t = 0; t < 4; ++t) {
            f32x4 d = __builtin_amdgcn_mfma_f32_16x16x16f16(xbT[mt], gz[t], zf4, 0, 0, 0);
#pragma unroll
            for (int r = 0; r < 4; ++r) Wlo[mt][t][r] -= cur.co15 * d[r];
          }
      }
    }
  };

  Ck2 cka, ckb;
  // producer preloads chunk 0 into cka; consumer's chunk 0 lands in ckb at iter 0
  if (isP) load_ck2(cka, Kp, S, coeff, brow, hoff, cobase, 0, q, ln);

  for (int i = 0; i < NC_; i += 2) {
    iter(i,     cka, ckb);
    iter(i + 1, ckb, cka);
  }
  iter(NC_, cka, ckb);   // final: consumer handles chunk NC_-1 (in cka)
}

extern "C" void kernel_launch(void* const* d_in, const int* in_sizes, int n_in,
                              void* d_out, int out_size, void* d_ws, size_t ws_size,
                              hipStream_t stream)
{
  const float* hid   = (const float*)d_in[0];
  const float* q_w   = (const float*)d_in[1];
  const float* k_w   = (const float*)d_in[2];
  const float* v_w   = (const float*)d_in[3];
  const float* o_w   = (const float*)d_in[4];
  const float* lin_w = (const float*)d_in[5];
  const float* lin_b = (const float*)d_in[6];
  const float* ln_w  = (const float*)d_in[7];
  const float* ln_b  = (const float*)d_in[8];
  const float* W1    = (const float*)d_in[9];
  const float* b1    = (const float*)d_in[10];
  float* out = (float*)d_out;

  const size_t BLC = (size_t)B_ * L_ * C_;
  const size_t CC  = (size_t)C_ * C_;
  _Float16* HF = (_Float16*)d_ws;               // hid f16; later scan output
  _Float16* WF = HF + BLC;
  _Float16* KF = WF + CC;
  _Float16* VF = KF + BLC;
  float*    CO = (float*)(VF + BLC);
  _Float16* QF = (_Float16*)d_out;              // Q f16 in d_out (dead before final GEMM)

  const int M = B_ * L_, N = C_, Kd = C_;
  dim3 gg(N / TN, M / TM);
  const int n8h = (int)(BLC / 8);
  const int n8w = (int)(CC / 8);

  cast_f16<<<(n8h+255)/256, 256, 0, stream>>>(hid, HF, n8h);
  cast_f16<<<(n8w+255)/256, 256, 0, stream>>>(q_w, WF, n8w);
  gemm_f16<_Float16><<<gg, 256, 0, stream>>>(HF, WF, QF, M, N, Kd);
  cast_f16<<<(n8w+255)/256, 256, 0, stream>>>(k_w, WF, n8w);
  gemm_f16<_Float16><<<gg, 256, 0, stream>>>(HF, WF, KF, M, N, Kd);
  cast_f16<<<(n8w+255)/256, 256, 0, stream>>>(v_w, WF, n8w);
  gemm_f16<_Float16><<<gg, 256, 0, stream>>>(HF, WF, VF, M, N, Kd);
  ilr_kernel<<<M / 16, 256, 0, stream>>>(hid, lin_w, lin_b, CO);
  scan_kernel<<<B_ * NH_, 128, 0, stream>>>(QF, KF, VF, CO, W1, b1, ln_w, ln_b, HF);
  cast_f16<<<(n8w+255)/256, 256, 0, stream>>>(o_w, WF, n8w);
  gemm_f16<float><<<gg, 256, 0, stream>>>(HF, WF, out, M, N, Kd);
}